// Round 12
// baseline (419.951 us; speedup 1.0000x reference)
//
#include <hip/hip_runtime.h>

typedef __attribute__((ext_vector_type(8))) short short8;
typedef __attribute__((ext_vector_type(4))) float float4v;

#define NLAGS 9
#define HID 256
#define GSAMP 16
#define MROWS 144          // 9 lag-tiles of 16 samples (LAG-MAJOR: row = lag*16 + sample)
#define F32STR 260         // f32 row stride for final l3 buffer (unchanged r7 path)
#define NTHREADS 512
// bf16 tile-major region: 2 * 9 tiles * 4096 shorts = 73,728; f32 overlay needs
// 74,872 shorts; keep r7's 76,032-short (152,064 B) allocation -> 1 block/CU.
#define SBUF_SHORTS 76032

union S8 { short8 v; unsigned short u[8]; };

__device__ __forceinline__ float b2f(unsigned short u) {
  union { unsigned int i; float f; } c; c.i = ((unsigned int)u) << 16; return c.f;
}
__device__ __forceinline__ unsigned short f2b(float f) {
  union { float f; unsigned int i; } c; c.f = f;
  return (unsigned short)((c.i + 0x7FFFu + ((c.i >> 16) & 1u)) >> 16);  // RNE
}
__device__ __forceinline__ float sane(float x) {
  return (__builtin_isfinite(x) && fabsf(x) < 1e30f) ? x : 0.0f;
}
// HW packed f32->bf16 (RNE), 1 VALU op for 2 conversions
__device__ __forceinline__ unsigned int pkbf16(float lo, float hi) {
  unsigned int r;
  asm("v_cvt_pk_bf16_f32 %0, %1, %2" : "=v"(r) : "v"(lo), "v"(hi));
  return r;
}
// unclamped tanh: exp->0 gives -1, exp->inf gives +1; finite-in => finite-out
// BLACKLIST (r8-r10 bisect): bias-init-in-MFMA-C and exp2f-tanh both broke
// correctness (scheduling-dependent absmax). Keep bias-add in epilogue, __expf.
__device__ __forceinline__ float ftanh(float x) {
  float t = __expf(2.0f * x);
  return 1.0f - 2.0f * __builtin_amdgcn_rcpf(t + 1.0f);
}
__device__ __forceinline__ float4v mfma16(short8 a, short8 b, float4v c) {
  return __builtin_amdgcn_mfma_f32_16x16x32_bf16(a, b, c, 0, 0, 0);
}

// ---- tile-major bf16 LDS layout: [tile m][kk-block of 32 cols][row 0..15][col&31]
// K-loop wave read (m,kk): lanes cover base..base+1023 bytes contiguously -> no
// bank conflicts (m134 pattern). Helpers are the ONLY address authority.
__device__ __forceinline__ int tmC(int row, int c) {        // chunk c = col/8, 0..31
  return ((row >> 4) * 8 + (c >> 2)) * 512 + (row & 15) * 32 + (c & 3) * 8;
}
__device__ __forceinline__ int tmE(int row, int col) {      // single element
  return ((row >> 4) * 8 + (col >> 5)) * 512 + (row & 15) * 32 + (col & 31);
}

// ---- prep: f32 weights -> transposed bf16 copies in ws (sanitized once here) ----
// layout (bf16 elems): Wl2t[256][256] @0, Ww2t @65536, Wm1t[256][512] @131072,
//                      Wm2t[256][512] @262144, Ww1p[256][32] @393216 (K padded 8->32)
__global__ void prep_kernel(const float* __restrict__ Wl2,
                            const float* __restrict__ Ww2,
                            const float* __restrict__ Wm1,
                            const float* __restrict__ Wm2,
                            const float* __restrict__ Ww1,
                            unsigned short* __restrict__ ws)
{
  int idx = blockIdx.x * 256 + threadIdx.x;   // 0..401407
  if (idx < 65536) {
    int n = idx >> 8, k = idx & 255;
    ws[idx] = f2b(sane(Wl2[k * 256 + n]));
  } else if (idx < 131072) {
    int j = idx - 65536; int n = j >> 8, k = j & 255;
    ws[idx] = f2b(sane(Ww2[k * 256 + n]));
  } else if (idx < 262144) {
    int j = idx - 131072; int n = j >> 9, k = j & 511;
    ws[idx] = f2b(sane(Wm1[k * 256 + n]));
  } else if (idx < 393216) {
    int j = idx - 262144; int n = j >> 9, k = j & 511;
    ws[idx] = f2b(sane(Wm2[k * 256 + n]));
  } else if (idx < 401408) {
    int j = idx - 393216; int n = j >> 5, k = j & 31;
    ws[idx] = (k < 8) ? f2b(sane(Ww1[k * 256 + n])) : (unsigned short)0;
  }
}

__global__ void __launch_bounds__(NTHREADS, 2)
fused_kernel(const float* __restrict__ lags,
             const float* __restrict__ weather,
             const float* __restrict__ Wl1,
             const float* __restrict__ bl1,
             const float* __restrict__ gbn,
             const float* __restrict__ bbn,
             const float* __restrict__ bl2,
             const float* __restrict__ bw1,
             const float* __restrict__ bw2,
             const float* __restrict__ bm1,
             const float* __restrict__ bm2,
             const float* __restrict__ Wreg,
             const float* __restrict__ breg,
             const unsigned short* __restrict__ ws,
             float* __restrict__ out)
{
  __shared__ __align__(16) unsigned short sBuf[SBUF_SHORTS];  // 152,064 B
  unsigned short* sL = sBuf;
  unsigned short* sW = sBuf + 36864;      // 9 tiles * 4096 shorts

  const int tid = threadIdx.x;
  const int wave = tid >> 6;
  const int lane16 = tid & 15;
  const int g4 = (tid >> 4) & 3;
  const int s0 = blockIdx.x * GSAMP;

  const unsigned short* Wl2t = ws;
  const unsigned short* Ww2t = ws + 65536;
  const unsigned short* Wm1t = ws + 131072;
  const unsigned short* Wm2t = ws + 262144;
  const unsigned short* Ww1p = ws + 393216;

  const int c0 = wave * 32 + lane16;       // wave's two output columns
  const int c1 = wave * 32 + 16 + lane16;

  // in-register lag-axis aggregation: acc[m] indexed by lag tile m
  auto applyA = [&](float4v (&a)[9]) {
    #pragma unroll
    for (int i = 0; i < 4; ++i) {
      float v0=a[0][i],v1=a[1][i],v2=a[2][i],v3=a[3][i],v4=a[4][i];
      float v5=a[5][i],v6=a[6][i],v7=a[7][i],v8=a[8][i];
      a[0][i]=v8;
      a[1][i]=v0;
      a[2][i]=(1.f/3.f)*v0+(2.f/3.f)*v1;
      a[3][i]=0.2f*v0+0.4f*v1+0.4f*v2;
      a[4][i]=0.2f*v1+0.4f*v2+0.4f*v3;
      a[5][i]=0.2f*v2+0.4f*v3+0.4f*v4;
      a[6][i]=0.2f*v3+0.4f*v4+0.4f*v5;
      a[7][i]=0.25f*v4+0.5f*v5+0.25f*v6;
      a[8][i]=(1.f/3.f)*(v5+v6+v7);
    }
  };

  // ---- Phase A: l0 = BN(tanh(lag*Wl1+bl1)) -> sL, lag-major, tile-major ----
  {
    const float BNS = 0.99999500003750f;  // 1/sqrt(1+1e-5)
    const int samp = tid >> 5;            // 0..15
    const int chnk = tid & 31;            // fixed col chunk per thread
    const int h0 = chnk << 3;
    float4v w0 = *(const float4v*)(Wl1 + h0);
    float4v w1 = *(const float4v*)(Wl1 + h0 + 4);
    float4v a0 = *(const float4v*)(bl1 + h0);
    float4v a1 = *(const float4v*)(bl1 + h0 + 4);
    float4v g0 = *(const float4v*)(gbn + h0);
    float4v g1 = *(const float4v*)(gbn + h0 + 4);
    float4v q0 = *(const float4v*)(bbn + h0);
    float4v q1 = *(const float4v*)(bbn + h0 + 4);
    #pragma unroll
    for (int e = 0; e < 4; ++e) { g0[e] *= BNS; g1[e] *= BNS; }
    #pragma unroll
    for (int d = 0; d < 9; ++d) {         // d = lag
      int row = d * 16 + samp;
      float lag = lags[(s0 + samp) * NLAGS + d];
      float t[8];
      #pragma unroll
      for (int e = 0; e < 4; ++e) {
        float v = ftanh(fmaf(lag, w0[e], a0[e]));
        t[e] = fmaf(v, g0[e], q0[e]);
        float v2 = ftanh(fmaf(lag, w1[e], a1[e]));
        t[e + 4] = fmaf(v2, g1[e], q1[e]);
      }
      uint4 o;
      o.x = pkbf16(t[0], t[1]); o.y = pkbf16(t[2], t[3]);
      o.z = pkbf16(t[4], t[5]); o.w = pkbf16(t[6], t[7]);
      *(uint4*)(sL + tmC(row, chnk)) = o;
    }
  }

  // ---- Phase B: w0 = tanh(weather @ Ww1 + bw1) -> sW (K pad 8->32) ----
  {
    float4v acc0[9], acc1[9];
    short8 bf0 = *(const short8*)(Ww1p + c0 * 32 + g4 * 8);
    short8 bf1 = *(const short8*)(Ww1p + c1 * 32 + g4 * 8);
    #pragma unroll
    for (int m = 0; m < 9; ++m) {         // m = lag tile; row-in-tile = sample = lane16
      S8 a8;
      if (g4 == 0) {
        const float* wp = weather + (size_t)(s0 + lane16) * 72 + m * 8;
        float4v x0 = *(const float4v*)(wp);
        float4v x1 = *(const float4v*)(wp + 4);
        a8.v = (short8){0,0,0,0,0,0,0,0};
        unsigned int p0 = pkbf16(x0[0], x0[1]), p1 = pkbf16(x0[2], x0[3]);
        unsigned int p2 = pkbf16(x1[0], x1[1]), p3 = pkbf16(x1[2], x1[3]);
        a8.u[0] = (unsigned short)p0; a8.u[1] = (unsigned short)(p0 >> 16);
        a8.u[2] = (unsigned short)p1; a8.u[3] = (unsigned short)(p1 >> 16);
        a8.u[4] = (unsigned short)p2; a8.u[5] = (unsigned short)(p2 >> 16);
        a8.u[6] = (unsigned short)p3; a8.u[7] = (unsigned short)(p3 >> 16);
      } else {
        a8.v = (short8){0,0,0,0,0,0,0,0};
      }
      float4v zz = {0.f, 0.f, 0.f, 0.f};
      acc0[m] = mfma16(a8.v, bf0, zz);
      acc1[m] = mfma16(a8.v, bf1, zz);
    }
    float bia0 = bw1[c0], bia1 = bw1[c1];
    #pragma unroll
    for (int m = 0; m < 9; ++m) {
      #pragma unroll
      for (int i = 0; i < 4; ++i) {
        int row = m * 16 + g4 * 4 + i;    // C/D: col=lane&15, row=(lane>>4)*4+i
        unsigned int p = pkbf16(ftanh(acc0[m][i] + bia0), ftanh(acc1[m][i] + bia1));
        sW[tmE(row, c0)] = (unsigned short)p;
        sW[tmE(row, c1)] = (unsigned short)(p >> 16);
      }
    }
  }
  __syncthreads();

  // ---- in-place GEMM (K=256): X = tanh(X @ W + b) ----
  auto gemm256 = [&](unsigned short* Abuf, const unsigned short* Bt, const float* bias) {
    float4v acc0[9], acc1[9];
    #pragma unroll
    for (int m = 0; m < 9; ++m) {
      float4v z = {0.f,0.f,0.f,0.f};
      acc0[m] = z; acc1[m] = z;
    }
    #pragma unroll
    for (int kk = 0; kk < 8; ++kk) {
      short8 b0 = *(const short8*)(Bt + c0 * 256 + kk * 32 + g4 * 8);
      short8 b1 = *(const short8*)(Bt + c1 * 256 + kk * 32 + g4 * 8);
      #pragma unroll
      for (int m = 0; m < 9; ++m) {
        short8 a = *(const short8*)(Abuf + tmC(m * 16 + lane16, kk * 4 + g4));
        acc0[m] = mfma16(a, b0, acc0[m]);
        acc1[m] = mfma16(a, b1, acc1[m]);
      }
    }
    __syncthreads();   // all waves' A reads complete before in-place overwrite
    float bia0 = bias[c0], bia1 = bias[c1];
    #pragma unroll
    for (int m = 0; m < 9; ++m) {
      #pragma unroll
      for (int i = 0; i < 4; ++i) {
        int row = m * 16 + g4 * 4 + i;
        unsigned int p = pkbf16(ftanh(acc0[m][i] + bia0), ftanh(acc1[m][i] + bia1));
        Abuf[tmE(row, c0)] = (unsigned short)p;
        Abuf[tmE(row, c1)] = (unsigned short)(p >> 16);
      }
    }
    __syncthreads();
  };

  gemm256(sL, Wl2t, bl2);   // l1 (lag-major)
  gemm256(sW, Ww2t, bw2);   // w1 -- sW is FINAL after this; never rewritten

  // ---- merge1: l2 = A·(l1@Wm1top + w1@Wm1bot) + bm1  -> sL ----
  {
    float4v acc0[9], acc1[9];
    #pragma unroll
    for (int m = 0; m < 9; ++m) {
      float4v z = {0.f,0.f,0.f,0.f};
      acc0[m] = z; acc1[m] = z;
    }
    #pragma unroll
    for (int kk = 0; kk < 16; ++kk) {
      const unsigned short* Ab = (kk < 8) ? sL : sW;
      int ko = kk & 7;
      short8 b0 = *(const short8*)(Wm1t + c0 * 512 + kk * 32 + g4 * 8);
      short8 b1 = *(const short8*)(Wm1t + c1 * 512 + kk * 32 + g4 * 8);
      #pragma unroll
      for (int m = 0; m < 9; ++m) {
        short8 a = *(const short8*)(Ab + tmC(m * 16 + lane16, ko * 4 + g4));
        acc0[m] = mfma16(a, b0, acc0[m]);
        acc1[m] = mfma16(a, b1, acc1[m]);
      }
    }
    __syncthreads();   // all sL reads complete before overwrite
    applyA(acc0); applyA(acc1);
    float bia0 = bm1[c0], bia1 = bm1[c1];
    #pragma unroll
    for (int m = 0; m < 9; ++m) {
      #pragma unroll
      for (int i = 0; i < 4; ++i) {
        int row = m * 16 + g4 * 4 + i;
        unsigned int p = pkbf16(acc0[m][i] + bia0, acc1[m][i] + bia1);
        sL[tmE(row, c0)] = (unsigned short)p;
        sL[tmE(row, c1)] = (unsigned short)(p >> 16);
      }
    }
    __syncthreads();
  }

  // ---- merge2: l3 = A·( l2@Wm2top + A·(w1@Wm2bot) ) + bm2  -> f32 LDS ----
  {
    float4v acc0[9], acc1[9];
    #pragma unroll
    for (int m = 0; m < 9; ++m) {
      float4v z = {0.f,0.f,0.f,0.f};
      acc0[m] = z; acc1[m] = z;
    }
    #pragma unroll
    for (int kk = 0; kk < 8; ++kk) {      // w-half: w1 @ Wm2bot (K 256..511)
      short8 b0 = *(const short8*)(Wm2t + c0 * 512 + (kk + 8) * 32 + g4 * 8);
      short8 b1 = *(const short8*)(Wm2t + c1 * 512 + (kk + 8) * 32 + g4 * 8);
      #pragma unroll
      for (int m = 0; m < 9; ++m) {
        short8 a = *(const short8*)(sW + tmC(m * 16 + lane16, kk * 4 + g4));
        acc0[m] = mfma16(a, b0, acc0[m]);
        acc1[m] = mfma16(a, b1, acc1[m]);
      }
    }
    applyA(acc0); applyA(acc1);           // inner A (w-path), pure registers
    #pragma unroll
    for (int kk = 0; kk < 8; ++kk) {      // l-half: l2 @ Wm2top, accumulate on top
      short8 b0 = *(const short8*)(Wm2t + c0 * 512 + kk * 32 + g4 * 8);
      short8 b1 = *(const short8*)(Wm2t + c1 * 512 + kk * 32 + g4 * 8);
      #pragma unroll
      for (int m = 0; m < 9; ++m) {
        short8 a = *(const short8*)(sL + tmC(m * 16 + lane16, kk * 4 + g4));
        acc0[m] = mfma16(a, b0, acc0[m]);
        acc1[m] = mfma16(a, b1, acc1[m]);
      }
    }
    __syncthreads();   // all sL/sW reads complete before f32 overwrite of sBuf
    applyA(acc0); applyA(acc1);           // outer A
    float bia0 = bm2[c0], bia1 = bm2[c1];
    float* f3 = (float*)sBuf;
    #pragma unroll
    for (int m = 0; m < 9; ++m) {
      #pragma unroll
      for (int i = 0; i < 4; ++i) {
        int row = m * 16 + g4 * 4 + i;
        f3[row * F32STR + c0] = acc0[m][i] + bia0;
        f3[row * F32STR + c1] = acc1[m][i] + bia1;
      }
    }
    __syncthreads();
  }

  // ---- final regression: out[b] = sum_{d,h} l3[d*16+s][h] * Wreg[d*256+h] + breg ----
  {
    int s = tid >> 5;
    int t32 = tid & 31;
    int h0 = t32 << 3;
    const float* f3 = (const float*)sBuf;
    float sum = 0.f;
    #pragma unroll
    for (int d = 0; d < 9; ++d) {
      const float* rp = f3 + (d * 16 + s) * F32STR + h0;
      float4v x0 = *(const float4v*)(rp);
      float4v x1 = *(const float4v*)(rp + 4);
      float4v r0 = *(const float4v*)(Wreg + d * 256 + h0);
      float4v r1 = *(const float4v*)(Wreg + d * 256 + h0 + 4);
      #pragma unroll
      for (int e = 0; e < 4; ++e) sum = fmaf(x0[e], r0[e], sum);
      #pragma unroll
      for (int e = 0; e < 4; ++e) sum = fmaf(x1[e], r1[e], sum);
    }
    sum += __shfl_down(sum, 16, 32);
    sum += __shfl_down(sum, 8, 32);
    sum += __shfl_down(sum, 4, 32);
    sum += __shfl_down(sum, 2, 32);
    sum += __shfl_down(sum, 1, 32);
    if (t32 == 0) out[s0 + s] = sum + breg[0];
  }
}

extern "C" void kernel_launch(void* const* d_in, const int* in_sizes, int n_in,
                              void* d_out, int out_size, void* d_ws, size_t ws_size,
                              hipStream_t stream) {
  const float* lags    = (const float*)d_in[0];
  const float* weather = (const float*)d_in[1];
  const float* Wl1     = (const float*)d_in[2];
  const float* bl1     = (const float*)d_in[3];
  const float* gbn     = (const float*)d_in[4];
  const float* bbn     = (const float*)d_in[5];
  const float* Wl2     = (const float*)d_in[6];
  const float* bl2     = (const float*)d_in[7];
  const float* Ww1     = (const float*)d_in[8];
  const float* bw1     = (const float*)d_in[9];
  const float* Ww2     = (const float*)d_in[10];
  const float* bw2     = (const float*)d_in[11];
  const float* Wm1     = (const float*)d_in[12];
  const float* bm1     = (const float*)d_in[13];
  const float* Wm2     = (const float*)d_in[14];
  const float* bm2     = (const float*)d_in[15];
  const float* Wreg    = (const float*)d_in[16];
  const float* breg    = (const float*)d_in[17];
  unsigned short* ws = (unsigned short*)d_ws;

  prep_kernel<<<1568, 256, 0, stream>>>(Wl2, Ww2, Wm1, Wm2, Ww1, ws);

  const int nblocks = 32768 / GSAMP;  // 2048
  fused_kernel<<<nblocks, NTHREADS, 0, stream>>>(
      lags, weather, Wl1, bl1, gbn, bbn, bl2, bw1, bw2, bm1, bm2,
      Wreg, breg, ws, (float*)d_out);
}

// Round 13
// 400.359 us; speedup vs baseline: 1.0489x; 1.0489x over previous
//
#include <hip/hip_runtime.h>

typedef __attribute__((ext_vector_type(8))) short short8;
typedef __attribute__((ext_vector_type(4))) float float4v;

#define NLAGS 9
#define HID 256
#define GSAMP 16
#define MROWS 144          // 9 lag-tiles of 16 samples (LAG-MAJOR: row = lag*16 + sample)
#define NTHREADS 512
#define SBUF_SHORTS 73728  // 2 * 9 tiles * 4096 shorts = 147,456 B (1 block/CU)

union S8 { short8 v; unsigned short u[8]; };

__device__ __forceinline__ float b2f(unsigned short u) {
  union { unsigned int i; float f; } c; c.i = ((unsigned int)u) << 16; return c.f;
}
__device__ __forceinline__ unsigned short f2b(float f) {
  union { float f; unsigned int i; } c; c.f = f;
  return (unsigned short)((c.i + 0x7FFFu + ((c.i >> 16) & 1u)) >> 16);  // RNE
}
__device__ __forceinline__ float sane(float x) {
  return (__builtin_isfinite(x) && fabsf(x) < 1e30f) ? x : 0.0f;
}
// HW packed f32->bf16 (RNE), 1 VALU op for 2 conversions
__device__ __forceinline__ unsigned int pkbf16(float lo, float hi) {
  unsigned int r;
  asm("v_cvt_pk_bf16_f32 %0, %1, %2" : "=v"(r) : "v"(lo), "v"(hi));
  return r;
}
// unclamped tanh: exp->0 gives -1, exp->inf gives +1; finite-in => finite-out
// BLACKLIST (r8-r10 bisect): bias-init-in-MFMA-C and exp2f-tanh both broke
// correctness (scheduling-dependent absmax). Keep bias-add in epilogue, __expf.
__device__ __forceinline__ float ftanh(float x) {
  float t = __expf(2.0f * x);
  return 1.0f - 2.0f * __builtin_amdgcn_rcpf(t + 1.0f);
}
__device__ __forceinline__ float4v mfma16(short8 a, short8 b, float4v c) {
  return __builtin_amdgcn_mfma_f32_16x16x32_bf16(a, b, c, 0, 0, 0);
}

// ---- tile-major bf16 LDS layout: [tile m][kk-block of 32 cols][row 0..15][col&31]
__device__ __forceinline__ int tmC(int row, int c) {        // chunk c = col/8, 0..31
  return ((row >> 4) * 8 + (c >> 2)) * 512 + (row & 15) * 32 + (c & 3) * 8;
}
__device__ __forceinline__ int tmE(int row, int col) {      // single element
  return ((row >> 4) * 8 + (col >> 5)) * 512 + (row & 15) * 32 + (col & 31);
}

// ---- prep: f32 weights -> transposed bf16 copies in ws (sanitized once here) ----
// layout (bf16 elems): Wl2t[256][256] @0, Ww2t @65536, Wm1t[256][512] @131072,
//                      Wm2t[256][512] @262144, Ww1p[256][32] @393216 (K padded 8->32)
__global__ void prep_kernel(const float* __restrict__ Wl2,
                            const float* __restrict__ Ww2,
                            const float* __restrict__ Wm1,
                            const float* __restrict__ Wm2,
                            const float* __restrict__ Ww1,
                            unsigned short* __restrict__ ws)
{
  int idx = blockIdx.x * 256 + threadIdx.x;   // 0..401407
  if (idx < 65536) {
    int n = idx >> 8, k = idx & 255;
    ws[idx] = f2b(sane(Wl2[k * 256 + n]));
  } else if (idx < 131072) {
    int j = idx - 65536; int n = j >> 8, k = j & 255;
    ws[idx] = f2b(sane(Ww2[k * 256 + n]));
  } else if (idx < 262144) {
    int j = idx - 131072; int n = j >> 9, k = j & 511;
    ws[idx] = f2b(sane(Wm1[k * 256 + n]));
  } else if (idx < 393216) {
    int j = idx - 262144; int n = j >> 9, k = j & 511;
    ws[idx] = f2b(sane(Wm2[k * 256 + n]));
  } else if (idx < 401408) {
    int j = idx - 393216; int n = j >> 5, k = j & 31;
    ws[idx] = (k < 8) ? f2b(sane(Ww1[k * 256 + n])) : (unsigned short)0;
  }
}

__global__ void __launch_bounds__(NTHREADS, 2)
fused_kernel(const float* __restrict__ lags,
             const float* __restrict__ weather,
             const float* __restrict__ Wl1,
             const float* __restrict__ bl1,
             const float* __restrict__ gbn,
             const float* __restrict__ bbn,
             const float* __restrict__ bl2,
             const float* __restrict__ bw1,
             const float* __restrict__ bw2,
             const float* __restrict__ bm1,
             const float* __restrict__ bm2,
             const float* __restrict__ Wreg,
             const float* __restrict__ breg,
             const unsigned short* __restrict__ ws,
             float* __restrict__ out)
{
  __shared__ __align__(16) unsigned short sBuf[SBUF_SHORTS];  // 147,456 B
  unsigned short* sL = sBuf;
  unsigned short* sW = sBuf + 36864;      // 9 tiles * 4096 shorts

  const int tid = threadIdx.x;
  const int wave = tid >> 6;
  const int lane16 = tid & 15;
  const int g4 = (tid >> 4) & 3;
  const int s0 = blockIdx.x * GSAMP;

  const unsigned short* Wl2t = ws;
  const unsigned short* Ww2t = ws + 65536;
  const unsigned short* Wm1t = ws + 131072;
  const unsigned short* Wm2t = ws + 262144;
  const unsigned short* Ww1p = ws + 393216;

  const int c0 = wave * 32 + lane16;       // wave's two output columns
  const int c1 = wave * 32 + 16 + lane16;

  // in-register lag-axis aggregation: acc[m] indexed by lag tile m
  auto applyA = [&](float4v (&a)[9]) {
    #pragma unroll
    for (int i = 0; i < 4; ++i) {
      float v0=a[0][i],v1=a[1][i],v2=a[2][i],v3=a[3][i],v4=a[4][i];
      float v5=a[5][i],v6=a[6][i],v7=a[7][i],v8=a[8][i];
      a[0][i]=v8;
      a[1][i]=v0;
      a[2][i]=(1.f/3.f)*v0+(2.f/3.f)*v1;
      a[3][i]=0.2f*v0+0.4f*v1+0.4f*v2;
      a[4][i]=0.2f*v1+0.4f*v2+0.4f*v3;
      a[5][i]=0.2f*v2+0.4f*v3+0.4f*v4;
      a[6][i]=0.2f*v3+0.4f*v4+0.4f*v5;
      a[7][i]=0.25f*v4+0.5f*v5+0.25f*v6;
      a[8][i]=(1.f/3.f)*(v5+v6+v7);
    }
  };

  // ---- Phase A: l0 = BN(tanh(lag*Wl1+bl1)) -> sL, lag-major, tile-major ----
  {
    const float BNS = 0.99999500003750f;  // 1/sqrt(1+1e-5)
    const int samp = tid >> 5;            // 0..15
    const int chnk = tid & 31;            // fixed col chunk per thread
    const int h0 = chnk << 3;
    float4v w0 = *(const float4v*)(Wl1 + h0);
    float4v w1 = *(const float4v*)(Wl1 + h0 + 4);
    float4v a0 = *(const float4v*)(bl1 + h0);
    float4v a1 = *(const float4v*)(bl1 + h0 + 4);
    float4v g0 = *(const float4v*)(gbn + h0);
    float4v g1 = *(const float4v*)(gbn + h0 + 4);
    float4v q0 = *(const float4v*)(bbn + h0);
    float4v q1 = *(const float4v*)(bbn + h0 + 4);
    #pragma unroll
    for (int e = 0; e < 4; ++e) { g0[e] *= BNS; g1[e] *= BNS; }
    #pragma unroll
    for (int d = 0; d < 9; ++d) {         // d = lag
      int row = d * 16 + samp;
      float lag = lags[(s0 + samp) * NLAGS + d];
      float t[8];
      #pragma unroll
      for (int e = 0; e < 4; ++e) {
        float v = ftanh(fmaf(lag, w0[e], a0[e]));
        t[e] = fmaf(v, g0[e], q0[e]);
        float v2 = ftanh(fmaf(lag, w1[e], a1[e]));
        t[e + 4] = fmaf(v2, g1[e], q1[e]);
      }
      uint4 o;
      o.x = pkbf16(t[0], t[1]); o.y = pkbf16(t[2], t[3]);
      o.z = pkbf16(t[4], t[5]); o.w = pkbf16(t[6], t[7]);
      *(uint4*)(sL + tmC(row, chnk)) = o;
    }
  }

  // ---- Phase B: w0 = tanh(weather @ Ww1 + bw1) -> sW (K pad 8->32) ----
  {
    float4v acc0[9], acc1[9];
    short8 bf0 = *(const short8*)(Ww1p + c0 * 32 + g4 * 8);
    short8 bf1 = *(const short8*)(Ww1p + c1 * 32 + g4 * 8);
    #pragma unroll
    for (int m = 0; m < 9; ++m) {         // m = lag tile; row-in-tile = sample = lane16
      S8 a8;
      if (g4 == 0) {
        const float* wp = weather + (size_t)(s0 + lane16) * 72 + m * 8;
        float4v x0 = *(const float4v*)(wp);
        float4v x1 = *(const float4v*)(wp + 4);
        a8.v = (short8){0,0,0,0,0,0,0,0};
        unsigned int p0 = pkbf16(x0[0], x0[1]), p1 = pkbf16(x0[2], x0[3]);
        unsigned int p2 = pkbf16(x1[0], x1[1]), p3 = pkbf16(x1[2], x1[3]);
        a8.u[0] = (unsigned short)p0; a8.u[1] = (unsigned short)(p0 >> 16);
        a8.u[2] = (unsigned short)p1; a8.u[3] = (unsigned short)(p1 >> 16);
        a8.u[4] = (unsigned short)p2; a8.u[5] = (unsigned short)(p2 >> 16);
        a8.u[6] = (unsigned short)p3; a8.u[7] = (unsigned short)(p3 >> 16);
      } else {
        a8.v = (short8){0,0,0,0,0,0,0,0};
      }
      float4v zz = {0.f, 0.f, 0.f, 0.f};
      acc0[m] = mfma16(a8.v, bf0, zz);
      acc1[m] = mfma16(a8.v, bf1, zz);
    }
    float bia0 = bw1[c0], bia1 = bw1[c1];
    #pragma unroll
    for (int m = 0; m < 9; ++m) {
      #pragma unroll
      for (int i = 0; i < 4; ++i) {
        int row = m * 16 + g4 * 4 + i;    // C/D: col=lane&15, row=(lane>>4)*4+i
        unsigned int p = pkbf16(ftanh(acc0[m][i] + bia0), ftanh(acc1[m][i] + bia1));
        sW[tmE(row, c0)] = (unsigned short)p;
        sW[tmE(row, c1)] = (unsigned short)(p >> 16);
      }
    }
  }
  __syncthreads();   // B1: sL (PhaseA) + sW (PhaseB) published

  // ---- in-place GEMM (K=256): X = tanh(X @ W + b) ----
  // trailing=false is safe when the NEXT phase does not touch Abuf before a
  // barrier (gemm(sL): gemm(sW) reads only sW; merge1 ordering flows via B3/B4).
  auto gemm256 = [&](unsigned short* Abuf, const unsigned short* Bt,
                     const float* bias, bool trailing) {
    float4v acc0[9], acc1[9];
    #pragma unroll
    for (int m = 0; m < 9; ++m) {
      float4v z = {0.f,0.f,0.f,0.f};
      acc0[m] = z; acc1[m] = z;
    }
    #pragma unroll
    for (int kk = 0; kk < 8; ++kk) {
      short8 b0 = *(const short8*)(Bt + c0 * 256 + kk * 32 + g4 * 8);
      short8 b1 = *(const short8*)(Bt + c1 * 256 + kk * 32 + g4 * 8);
      #pragma unroll
      for (int m = 0; m < 9; ++m) {
        short8 a = *(const short8*)(Abuf + tmC(m * 16 + lane16, kk * 4 + g4));
        acc0[m] = mfma16(a, b0, acc0[m]);
        acc1[m] = mfma16(a, b1, acc1[m]);
      }
    }
    __syncthreads();   // all waves' A reads complete before in-place overwrite
    float bia0 = bias[c0], bia1 = bias[c1];
    #pragma unroll
    for (int m = 0; m < 9; ++m) {
      #pragma unroll
      for (int i = 0; i < 4; ++i) {
        int row = m * 16 + g4 * 4 + i;
        unsigned int p = pkbf16(ftanh(acc0[m][i] + bia0), ftanh(acc1[m][i] + bia1));
        Abuf[tmE(row, c0)] = (unsigned short)p;
        Abuf[tmE(row, c1)] = (unsigned short)(p >> 16);
      }
    }
    if (trailing) __syncthreads();
  };

  gemm256(sL, Wl2t, bl2, false);  // l1; epilogue overlaps gemm(sW) K-loop
  gemm256(sW, Ww2t, bw2, true);   // w1 (B3 internal, B4 trailing); sW final

  // ---- merge1: l2 = A·(l1@Wm1top + w1@Wm1bot) + bm1  -> sL ----
  {
    float4v acc0[9], acc1[9];
    #pragma unroll
    for (int m = 0; m < 9; ++m) {
      float4v z = {0.f,0.f,0.f,0.f};
      acc0[m] = z; acc1[m] = z;
    }
    #pragma unroll
    for (int kk = 0; kk < 16; ++kk) {
      const unsigned short* Ab = (kk < 8) ? sL : sW;
      int ko = kk & 7;
      short8 b0 = *(const short8*)(Wm1t + c0 * 512 + kk * 32 + g4 * 8);
      short8 b1 = *(const short8*)(Wm1t + c1 * 512 + kk * 32 + g4 * 8);
      #pragma unroll
      for (int m = 0; m < 9; ++m) {
        short8 a = *(const short8*)(Ab + tmC(m * 16 + lane16, ko * 4 + g4));
        acc0[m] = mfma16(a, b0, acc0[m]);
        acc1[m] = mfma16(a, b1, acc1[m]);
      }
    }
    __syncthreads();   // B5: all sL/sW reads complete before sL overwrite
    applyA(acc0); applyA(acc1);
    float bia0 = bm1[c0], bia1 = bm1[c1];
    #pragma unroll
    for (int m = 0; m < 9; ++m) {
      #pragma unroll
      for (int i = 0; i < 4; ++i) {
        int row = m * 16 + g4 * 4 + i;
        unsigned int p = pkbf16(acc0[m][i] + bia0, acc1[m][i] + bia1);
        sL[tmE(row, c0)] = (unsigned short)p;
        sL[tmE(row, c1)] = (unsigned short)(p >> 16);
      }
    }
    // no trailing barrier: merge2 w-half reads only sW; B6 publishes sL
  }

  // ---- merge2 + fused regression:
  //      l3 = A·( l2@Wm2top + A·(w1@Wm2bot) ) + bm2 ; out = l3·Wreg + breg ----
  {
    float4v acc0[9], acc1[9];
    #pragma unroll
    for (int m = 0; m < 9; ++m) {
      float4v z = {0.f,0.f,0.f,0.f};
      acc0[m] = z; acc1[m] = z;
    }
    #pragma unroll
    for (int kk = 0; kk < 8; ++kk) {      // w-half: w1 @ Wm2bot (K 256..511)
      short8 b0 = *(const short8*)(Wm2t + c0 * 512 + (kk + 8) * 32 + g4 * 8);
      short8 b1 = *(const short8*)(Wm2t + c1 * 512 + (kk + 8) * 32 + g4 * 8);
      #pragma unroll
      for (int m = 0; m < 9; ++m) {
        short8 a = *(const short8*)(sW + tmC(m * 16 + lane16, kk * 4 + g4));
        acc0[m] = mfma16(a, b0, acc0[m]);
        acc1[m] = mfma16(a, b1, acc1[m]);
      }
    }
    applyA(acc0); applyA(acc1);           // inner A (w-path), pure registers
    __syncthreads();   // B6: merge1 sL-writes visible; all w-half sW reads drained
    // hoist final-dot operands (L2-hot; hides load latency under l-half K-loop)
    float r0v[9], r1v[9];
    #pragma unroll
    for (int m = 0; m < 9; ++m) {
      r0v[m] = Wreg[m * 256 + c0];
      r1v[m] = Wreg[m * 256 + c1];
    }
    float bia0 = bm2[c0], bia1 = bm2[c1];
    #pragma unroll
    for (int kk = 0; kk < 8; ++kk) {      // l-half: l2 @ Wm2top, accumulate on top
      short8 b0 = *(const short8*)(Wm2t + c0 * 512 + kk * 32 + g4 * 8);
      short8 b1 = *(const short8*)(Wm2t + c1 * 512 + kk * 32 + g4 * 8);
      #pragma unroll
      for (int m = 0; m < 9; ++m) {
        short8 a = *(const short8*)(sL + tmC(m * 16 + lane16, kk * 4 + g4));
        acc0[m] = mfma16(a, b0, acc0[m]);
        acc1[m] = mfma16(a, b1, acc1[m]);
      }
    }
    applyA(acc0); applyA(acc1);           // outer A; acc = l3 (minus bias)
    // per-lane partial dot for samples g4*4+i over cols {c0, c1}
    float P[4];
    #pragma unroll
    for (int i = 0; i < 4; ++i) {
      float p = 0.f;
      #pragma unroll
      for (int m = 0; m < 9; ++m) {
        p = fmaf(acc0[m][i] + bia0, r0v[m], p);
        p = fmaf(acc1[m][i] + bia1, r1v[m], p);
      }
      P[i] = p;
    }
    #pragma unroll
    for (int off = 8; off >= 1; off >>= 1) {   // reduce across lane16 groups
      #pragma unroll
      for (int i = 0; i < 4; ++i) P[i] += __shfl_down(P[i], off, 16);
    }
    float* scratch = (float*)sW;   // sW dead after B6-guarded w-half; disjoint from sL
    if (lane16 == 0) {
      #pragma unroll
      for (int i = 0; i < 4; ++i) scratch[wave * 16 + g4 * 4 + i] = P[i];
    }
    __syncthreads();   // B7: scratch published
    if (tid < GSAMP) {
      float sum = 0.f;
      #pragma unroll
      for (int w = 0; w < 8; ++w) sum += scratch[w * 16 + tid];
      out[s0 + tid] = sum + breg[0];
    }
  }
}

extern "C" void kernel_launch(void* const* d_in, const int* in_sizes, int n_in,
                              void* d_out, int out_size, void* d_ws, size_t ws_size,
                              hipStream_t stream) {
  const float* lags    = (const float*)d_in[0];
  const float* weather = (const float*)d_in[1];
  const float* Wl1     = (const float*)d_in[2];
  const float* bl1     = (const float*)d_in[3];
  const float* gbn     = (const float*)d_in[4];
  const float* bbn     = (const float*)d_in[5];
  const float* Wl2     = (const float*)d_in[6];
  const float* bl2     = (const float*)d_in[7];
  const float* Ww1     = (const float*)d_in[8];
  const float* bw1     = (const float*)d_in[9];
  const float* Ww2     = (const float*)d_in[10];
  const float* bw2     = (const float*)d_in[11];
  const float* Wm1     = (const float*)d_in[12];
  const float* bm1     = (const float*)d_in[13];
  const float* Wm2     = (const float*)d_in[14];
  const float* bm2     = (const float*)d_in[15];
  const float* Wreg    = (const float*)d_in[16];
  const float* breg    = (const float*)d_in[17];
  unsigned short* ws = (unsigned short*)d_ws;

  prep_kernel<<<1568, 256, 0, stream>>>(Wl2, Ww2, Wm1, Wm2, Ww1, ws);

  const int nblocks = 32768 / GSAMP;  // 2048
  fused_kernel<<<nblocks, NTHREADS, 0, stream>>>(
      lags, weather, Wl1, bl1, gbn, bbn, bl2, bw1, bw2, bm1, bm2,
      Wreg, breg, ws, (float*)d_out);
}

// Round 14
// 362.514 us; speedup vs baseline: 1.1584x; 1.1044x over previous
//
#include <hip/hip_runtime.h>

typedef __attribute__((ext_vector_type(8))) short short8;
typedef __attribute__((ext_vector_type(4))) float float4v;

#define NLAGS 9
#define HID 256
#define GSAMP 16
#define MROWS 144          // 9 lag-tiles of 16 samples (LAG-MAJOR: row = lag*16 + sample)
#define NTHREADS 512
// 2 * 9 tiles * 4096 shorts (sL,sW) + 256 shorts (512B f32 scratch) = 147,968 B
#define SBUF_SHORTS (73728 + 256)

union S8 { short8 v; unsigned short u[8]; };

__device__ __forceinline__ float b2f(unsigned short u) {
  union { unsigned int i; float f; } c; c.i = ((unsigned int)u) << 16; return c.f;
}
__device__ __forceinline__ unsigned short f2b(float f) {
  union { float f; unsigned int i; } c; c.f = f;
  return (unsigned short)((c.i + 0x7FFFu + ((c.i >> 16) & 1u)) >> 16);  // RNE
}
__device__ __forceinline__ float sane(float x) {
  return (__builtin_isfinite(x) && fabsf(x) < 1e30f) ? x : 0.0f;
}
// HW packed f32->bf16 (RNE), 1 VALU op for 2 conversions
__device__ __forceinline__ unsigned int pkbf16(float lo, float hi) {
  unsigned int r;
  asm("v_cvt_pk_bf16_f32 %0, %1, %2" : "=v"(r) : "v"(lo), "v"(hi));
  return r;
}
// unclamped tanh: exp->0 gives -1, exp->inf gives +1; finite-in => finite-out
// BLACKLIST (r8-r10 bisect): bias-init-in-MFMA-C and exp2f-tanh broke correctness.
__device__ __forceinline__ float ftanh(float x) {
  float t = __expf(2.0f * x);
  return 1.0f - 2.0f * __builtin_amdgcn_rcpf(t + 1.0f);
}
__device__ __forceinline__ float4v mfma16(short8 a, short8 b, float4v c) {
  return __builtin_amdgcn_mfma_f32_16x16x32_bf16(a, b, c, 0, 0, 0);
}

// ---- tile-major bf16 LDS layout: [tile m][kk-block of 32 cols][row 0..15][col&31]
__device__ __forceinline__ int tmC(int row, int c) {        // chunk c = col/8, 0..31
  return ((row >> 4) * 8 + (c >> 2)) * 512 + (row & 15) * 32 + (c & 3) * 8;
}
__device__ __forceinline__ int tmE(int row, int col) {      // single element
  return ((row >> 4) * 8 + (col >> 5)) * 512 + (row & 15) * 32 + (col & 31);
}

// ---- prep: f32 weights -> transposed bf16 copies in ws (sanitized once here) ----
// layout (bf16 elems): Wl2t[256][256] @0, Ww2t @65536, Wm1t[256][512] @131072,
//                      Ww1p[256][32] @262144 (K padded 8->32).  (Wm2 not staged:
//                      merge2 is algebraically folded into V1/V2'/C0 below.)
__global__ void prep_kernel(const float* __restrict__ Wl2,
                            const float* __restrict__ Ww2,
                            const float* __restrict__ Wm1,
                            const float* __restrict__ Ww1,
                            unsigned short* __restrict__ ws)
{
  int idx = blockIdx.x * 256 + threadIdx.x;   // 0..270335
  if (idx < 65536) {
    int n = idx >> 8, k = idx & 255;
    ws[idx] = f2b(sane(Wl2[k * 256 + n]));
  } else if (idx < 131072) {
    int j = idx - 65536; int n = j >> 8, k = j & 255;
    ws[idx] = f2b(sane(Ww2[k * 256 + n]));
  } else if (idx < 262144) {
    int j = idx - 131072; int n = j >> 9, k = j & 511;
    ws[idx] = f2b(sane(Wm1[k * 256 + n]));
  } else if (idx < 270336) {
    int j = idx - 262144; int n = j >> 5, k = j & 31;
    ws[idx] = (k < 8) ? f2b(sane(Ww1[k * 256 + n])) : (unsigned short)0;
  }
}

// ---- prep2: fold final-regression through merge2 (all f32, exact algebra) ----
// out[s] = <l2[s], V1> + <w1[s], V2'> + C0, with
//   W'  = A^T Wreg           (A row-stochastic => bias of merge2 folds to C0)
//   V1  = W' @ Wm2top^T      [9][256]
//   V2' = (A^T W') @ Wm2bot^T[9][256]
//   C0  = sum_{d,h} bm2[h] Wreg[d*256+h] + breg
// vtab (f32): V1 @0..2303, V2' @2304..4607, C0 @4608
__global__ void prep2_kernel(const float* __restrict__ Wm2,
                             const float* __restrict__ Wreg,
                             const float* __restrict__ bm2,
                             const float* __restrict__ breg,
                             float* __restrict__ vtab)
{
  const float A[9][9] = {
    {0,0,0,0,0,0,0,0,1},
    {1,0,0,0,0,0,0,0,0},
    {1.f/3,2.f/3,0,0,0,0,0,0,0},
    {0.2f,0.4f,0.4f,0,0,0,0,0,0},
    {0,0.2f,0.4f,0.4f,0,0,0,0,0},
    {0,0,0.2f,0.4f,0.4f,0,0,0,0},
    {0,0,0,0.2f,0.4f,0.4f,0,0,0},
    {0,0,0,0,0.25f,0.5f,0.25f,0,0},
    {0,0,0,0,0,1.f/3,1.f/3,1.f/3,0},
  };
  int idx = blockIdx.x * 256 + threadIdx.x;
  if (idx < 4608) {
    int mat = (idx >= 2304);              // 0: V1, 1: V2'
    int w = idx - mat * 2304;
    int d = w >> 8, k = w & 255;
    float coef[9];
    #pragma unroll
    for (int dp = 0; dp < 9; ++dp) {
      if (!mat) {
        coef[dp] = A[dp][d];              // (A^T)[d][dp]
      } else {
        float s = 0.f;                    // (A^2)[dp][d] = sum_e A[dp][e] A[e][d]
        #pragma unroll
        for (int e = 0; e < 9; ++e) s += A[dp][e] * A[e][d];
        coef[dp] = s;
      }
    }
    const float* wm2row = Wm2 + (size_t)(mat * 256 + k) * 256;
    float acc = 0.f;
    for (int h = 0; h < 256; ++h) {
      float wp = 0.f;
      #pragma unroll
      for (int dp = 0; dp < 9; ++dp) wp = fmaf(coef[dp], Wreg[dp * 256 + h], wp);
      acc = fmaf(wp, wm2row[h], acc);
    }
    vtab[idx] = acc;
  } else if (idx == 4608) {
    float c0 = breg[0];
    for (int d = 0; d < 9; ++d)
      for (int h = 0; h < 256; ++h) c0 = fmaf(bm2[h], Wreg[d * 256 + h], c0);
    vtab[4608] = c0;
  }
}

__global__ void __launch_bounds__(NTHREADS, 2)
fused_kernel(const float* __restrict__ lags,
             const float* __restrict__ weather,
             const float* __restrict__ Wl1,
             const float* __restrict__ bl1,
             const float* __restrict__ gbn,
             const float* __restrict__ bbn,
             const float* __restrict__ bl2,
             const float* __restrict__ bw1,
             const float* __restrict__ bw2,
             const float* __restrict__ bm1,
             const unsigned short* __restrict__ ws,
             const float* __restrict__ vtab,
             float* __restrict__ out)
{
  __shared__ __align__(16) unsigned short sBuf[SBUF_SHORTS];  // 147,968 B
  unsigned short* sL = sBuf;
  unsigned short* sW = sBuf + 36864;      // 9 tiles * 4096 shorts
  float* scratch = (float*)(sBuf + 73728);

  const int tid = threadIdx.x;
  const int wave = tid >> 6;
  const int lane16 = tid & 15;
  const int g4 = (tid >> 4) & 3;
  const int s0 = blockIdx.x * GSAMP;

  const unsigned short* Wl2t = ws;
  const unsigned short* Ww2t = ws + 65536;
  const unsigned short* Wm1t = ws + 131072;
  const unsigned short* Ww1p = ws + 262144;

  const int c0 = wave * 32 + lane16;       // wave's two output columns
  const int c1 = wave * 32 + 16 + lane16;

  // in-register lag-axis aggregation: acc[m] indexed by lag tile m
  auto applyA = [&](float4v (&a)[9]) {
    #pragma unroll
    for (int i = 0; i < 4; ++i) {
      float v0=a[0][i],v1=a[1][i],v2=a[2][i],v3=a[3][i],v4=a[4][i];
      float v5=a[5][i],v6=a[6][i],v7=a[7][i],v8=a[8][i];
      a[0][i]=v8;
      a[1][i]=v0;
      a[2][i]=(1.f/3.f)*v0+(2.f/3.f)*v1;
      a[3][i]=0.2f*v0+0.4f*v1+0.4f*v2;
      a[4][i]=0.2f*v1+0.4f*v2+0.4f*v3;
      a[5][i]=0.2f*v2+0.4f*v3+0.4f*v4;
      a[6][i]=0.2f*v3+0.4f*v4+0.4f*v5;
      a[7][i]=0.25f*v4+0.5f*v5+0.25f*v6;
      a[8][i]=(1.f/3.f)*(v5+v6+v7);
    }
  };

  // ---- Phase A: l0 = BN(tanh(lag*Wl1+bl1)) -> sL, lag-major, tile-major ----
  {
    const float BNS = 0.99999500003750f;  // 1/sqrt(1+1e-5)
    const int samp = tid >> 5;            // 0..15
    const int chnk = tid & 31;            // fixed col chunk per thread
    const int h0 = chnk << 3;
    float4v w0 = *(const float4v*)(Wl1 + h0);
    float4v w1 = *(const float4v*)(Wl1 + h0 + 4);
    float4v a0 = *(const float4v*)(bl1 + h0);
    float4v a1 = *(const float4v*)(bl1 + h0 + 4);
    float4v g0 = *(const float4v*)(gbn + h0);
    float4v g1 = *(const float4v*)(gbn + h0 + 4);
    float4v q0 = *(const float4v*)(bbn + h0);
    float4v q1 = *(const float4v*)(bbn + h0 + 4);
    #pragma unroll
    for (int e = 0; e < 4; ++e) { g0[e] *= BNS; g1[e] *= BNS; }
    #pragma unroll
    for (int d = 0; d < 9; ++d) {         // d = lag
      int row = d * 16 + samp;
      float lag = lags[(s0 + samp) * NLAGS + d];
      float t[8];
      #pragma unroll
      for (int e = 0; e < 4; ++e) {
        float v = ftanh(fmaf(lag, w0[e], a0[e]));
        t[e] = fmaf(v, g0[e], q0[e]);
        float v2 = ftanh(fmaf(lag, w1[e], a1[e]));
        t[e + 4] = fmaf(v2, g1[e], q1[e]);
      }
      uint4 o;
      o.x = pkbf16(t[0], t[1]); o.y = pkbf16(t[2], t[3]);
      o.z = pkbf16(t[4], t[5]); o.w = pkbf16(t[6], t[7]);
      *(uint4*)(sL + tmC(row, chnk)) = o;
    }
  }

  // ---- Phase B: w0 = tanh(weather @ Ww1 + bw1) -> sW (K pad 8->32) ----
  {
    float4v acc0[9], acc1[9];
    short8 bf0 = *(const short8*)(Ww1p + c0 * 32 + g4 * 8);
    short8 bf1 = *(const short8*)(Ww1p + c1 * 32 + g4 * 8);
    #pragma unroll
    for (int m = 0; m < 9; ++m) {         // m = lag tile; row-in-tile = sample = lane16
      S8 a8;
      if (g4 == 0) {
        const float* wp = weather + (size_t)(s0 + lane16) * 72 + m * 8;
        float4v x0 = *(const float4v*)(wp);
        float4v x1 = *(const float4v*)(wp + 4);
        a8.v = (short8){0,0,0,0,0,0,0,0};
        unsigned int p0 = pkbf16(x0[0], x0[1]), p1 = pkbf16(x0[2], x0[3]);
        unsigned int p2 = pkbf16(x1[0], x1[1]), p3 = pkbf16(x1[2], x1[3]);
        a8.u[0] = (unsigned short)p0; a8.u[1] = (unsigned short)(p0 >> 16);
        a8.u[2] = (unsigned short)p1; a8.u[3] = (unsigned short)(p1 >> 16);
        a8.u[4] = (unsigned short)p2; a8.u[5] = (unsigned short)(p2 >> 16);
        a8.u[6] = (unsigned short)p3; a8.u[7] = (unsigned short)(p3 >> 16);
      } else {
        a8.v = (short8){0,0,0,0,0,0,0,0};
      }
      float4v zz = {0.f, 0.f, 0.f, 0.f};
      acc0[m] = mfma16(a8.v, bf0, zz);
      acc1[m] = mfma16(a8.v, bf1, zz);
    }
    float bia0 = bw1[c0], bia1 = bw1[c1];
    #pragma unroll
    for (int m = 0; m < 9; ++m) {
      #pragma unroll
      for (int i = 0; i < 4; ++i) {
        int row = m * 16 + g4 * 4 + i;    // C/D: col=lane&15, row=(lane>>4)*4+i
        unsigned int p = pkbf16(ftanh(acc0[m][i] + bia0), ftanh(acc1[m][i] + bia1));
        sW[tmE(row, c0)] = (unsigned short)p;
        sW[tmE(row, c1)] = (unsigned short)(p >> 16);
      }
    }
  }
  __syncthreads();   // B1: sL (PhaseA) + sW (PhaseB) published

  // ---- gemm sL (K=256): l1 = tanh(l0 @ Wl2 + bl2), in-place ----
  {
    float4v acc0[9], acc1[9];
    #pragma unroll
    for (int m = 0; m < 9; ++m) {
      float4v z = {0.f,0.f,0.f,0.f};
      acc0[m] = z; acc1[m] = z;
    }
    #pragma unroll
    for (int kk = 0; kk < 8; ++kk) {
      short8 b0 = *(const short8*)(Wl2t + c0 * 256 + kk * 32 + g4 * 8);
      short8 b1 = *(const short8*)(Wl2t + c1 * 256 + kk * 32 + g4 * 8);
      #pragma unroll
      for (int m = 0; m < 9; ++m) {
        short8 a = *(const short8*)(sL + tmC(m * 16 + lane16, kk * 4 + g4));
        acc0[m] = mfma16(a, b0, acc0[m]);
        acc1[m] = mfma16(a, b1, acc1[m]);
      }
    }
    __syncthreads();   // B2: all sL reads complete before in-place overwrite
    float bia0 = bl2[c0], bia1 = bl2[c1];
    #pragma unroll
    for (int m = 0; m < 9; ++m) {
      #pragma unroll
      for (int i = 0; i < 4; ++i) {
        int row = m * 16 + g4 * 4 + i;
        unsigned int p = pkbf16(ftanh(acc0[m][i] + bia0), ftanh(acc1[m][i] + bia1));
        sL[tmE(row, c0)] = (unsigned short)p;
        sL[tmE(row, c1)] = (unsigned short)(p >> 16);
      }
    }
    // no trailing barrier: next K-loop reads only sW; B3 orders sL for merge1
  }

  // ---- gemm sW (K=256): w1 = tanh(w0 @ Ww2 + bw2), in-place; + P2 dot ----
  float P2[4] = {0.f, 0.f, 0.f, 0.f};
  {
    float4v acc0[9], acc1[9];
    #pragma unroll
    for (int m = 0; m < 9; ++m) {
      float4v z = {0.f,0.f,0.f,0.f};
      acc0[m] = z; acc1[m] = z;
    }
    #pragma unroll
    for (int kk = 0; kk < 8; ++kk) {
      short8 b0 = *(const short8*)(Ww2t + c0 * 256 + kk * 32 + g4 * 8);
      short8 b1 = *(const short8*)(Ww2t + c1 * 256 + kk * 32 + g4 * 8);
      #pragma unroll
      for (int m = 0; m < 9; ++m) {
        short8 a = *(const short8*)(sW + tmC(m * 16 + lane16, kk * 4 + g4));
        acc0[m] = mfma16(a, b0, acc0[m]);
        acc1[m] = mfma16(a, b1, acc1[m]);
      }
    }
    __syncthreads();   // B3: all sW reads complete before overwrite (also pubs sL)
    float v2c0[9], v2c1[9];
    #pragma unroll
    for (int m = 0; m < 9; ++m) {
      v2c0[m] = vtab[2304 + m * 256 + c0];
      v2c1[m] = vtab[2304 + m * 256 + c1];
    }
    float bia0 = bw2[c0], bia1 = bw2[c1];
    #pragma unroll
    for (int m = 0; m < 9; ++m) {
      #pragma unroll
      for (int i = 0; i < 4; ++i) {
        int row = m * 16 + g4 * 4 + i;
        float t0 = ftanh(acc0[m][i] + bia0);
        float t1 = ftanh(acc1[m][i] + bia1);
        P2[i] = fmaf(t0, v2c0[m], P2[i]);     // <w1, V2'> partial (f32, pre-pack)
        P2[i] = fmaf(t1, v2c1[m], P2[i]);
        unsigned int p = pkbf16(t0, t1);
        sW[tmE(row, c0)] = (unsigned short)p;
        sW[tmE(row, c1)] = (unsigned short)(p >> 16);
      }
    }
    // no trailing barrier: merge1 reads sL first; B4 publishes sW mid-loop
  }

  // ---- merge1 + fused output:
  //      l2 = A·(l1@Wm1top + w1@Wm1bot) + bm1  (registers only);
  //      out = <l2,V1> + P2 + C0 ----
  {
    float4v acc0[9], acc1[9];
    #pragma unroll
    for (int m = 0; m < 9; ++m) {
      float4v z = {0.f,0.f,0.f,0.f};
      acc0[m] = z; acc1[m] = z;
    }
    #pragma unroll
    for (int kk = 0; kk < 8; ++kk) {      // l-half: reads sL (stable since B3)
      short8 b0 = *(const short8*)(Wm1t + c0 * 512 + kk * 32 + g4 * 8);
      short8 b1 = *(const short8*)(Wm1t + c1 * 512 + kk * 32 + g4 * 8);
      #pragma unroll
      for (int m = 0; m < 9; ++m) {
        short8 a = *(const short8*)(sL + tmC(m * 16 + lane16, kk * 4 + g4));
        acc0[m] = mfma16(a, b0, acc0[m]);
        acc1[m] = mfma16(a, b1, acc1[m]);
      }
    }
    __syncthreads();   // B4: gemm-sW epilogue's sW writes published
    float v1c0[9], v1c1[9];
    #pragma unroll
    for (int m = 0; m < 9; ++m) {
      v1c0[m] = vtab[m * 256 + c0];
      v1c1[m] = vtab[m * 256 + c1];
    }
    #pragma unroll
    for (int kk = 8; kk < 16; ++kk) {     // w-half: reads sW
      short8 b0 = *(const short8*)(Wm1t + c0 * 512 + kk * 32 + g4 * 8);
      short8 b1 = *(const short8*)(Wm1t + c1 * 512 + kk * 32 + g4 * 8);
      #pragma unroll
      for (int m = 0; m < 9; ++m) {
        short8 a = *(const short8*)(sW + tmC(m * 16 + lane16, (kk - 8) * 4 + g4));
        acc0[m] = mfma16(a, b0, acc0[m]);
        acc1[m] = mfma16(a, b1, acc1[m]);
      }
    }
    applyA(acc0); applyA(acc1);           // l2 (minus bias) in registers
    float bia0 = bm1[c0], bia1 = bm1[c1];
    float P[4];
    #pragma unroll
    for (int i = 0; i < 4; ++i) {
      float p = P2[i];
      #pragma unroll
      for (int m = 0; m < 9; ++m) {
        p = fmaf(acc0[m][i] + bia0, v1c0[m], p);   // <l2, V1> partial, f32
        p = fmaf(acc1[m][i] + bia1, v1c1[m], p);
      }
      P[i] = p;
    }
    #pragma unroll
    for (int off = 8; off >= 1; off >>= 1) {   // reduce across lane16 groups
      #pragma unroll
      for (int i = 0; i < 4; ++i) P[i] += __shfl_down(P[i], off, 16);
    }
    if (lane16 == 0) {
      #pragma unroll
      for (int i = 0; i < 4; ++i) scratch[wave * 16 + g4 * 4 + i] = P[i];
    }
  }
  __syncthreads();   // B5: scratch published
  if (tid < GSAMP) {
    float sum = 0.f;
    #pragma unroll
    for (int w = 0; w < 8; ++w) sum += scratch[w * 16 + tid];
    out[s0 + tid] = sum + vtab[4608];     // + C0 (includes breg)
  }
}

extern "C" void kernel_launch(void* const* d_in, const int* in_sizes, int n_in,
                              void* d_out, int out_size, void* d_ws, size_t ws_size,
                              hipStream_t stream) {
  const float* lags    = (const float*)d_in[0];
  const float* weather = (const float*)d_in[1];
  const float* Wl1     = (const float*)d_in[2];
  const float* bl1     = (const float*)d_in[3];
  const float* gbn     = (const float*)d_in[4];
  const float* bbn     = (const float*)d_in[5];
  const float* Wl2     = (const float*)d_in[6];
  const float* bl2     = (const float*)d_in[7];
  const float* Ww1     = (const float*)d_in[8];
  const float* bw1     = (const float*)d_in[9];
  const float* Ww2     = (const float*)d_in[10];
  const float* bw2     = (const float*)d_in[11];
  const float* Wm1     = (const float*)d_in[12];
  const float* bm1     = (const float*)d_in[13];
  const float* Wm2     = (const float*)d_in[14];
  const float* bm2     = (const float*)d_in[15];
  const float* Wreg    = (const float*)d_in[16];
  const float* breg    = (const float*)d_in[17];
  unsigned short* ws = (unsigned short*)d_ws;
  float* vtab = (float*)(ws + 270336);    // byte offset 540,672 (16B-aligned)

  prep_kernel<<<1056, 256, 0, stream>>>(Wl2, Ww2, Wm1, Ww1, ws);
  prep2_kernel<<<19, 256, 0, stream>>>(Wm2, Wreg, bm2, breg, vtab);

  const int nblocks = 32768 / GSAMP;  // 2048
  fused_kernel<<<nblocks, NTHREADS, 0, stream>>>(
      lags, weather, Wl1, bl1, gbn, bbn, bl2, bw1, bw2, bm1,
      ws, vtab, (float*)d_out);
}

// Round 15
// 320.817 us; speedup vs baseline: 1.3090x; 1.1300x over previous
//
#include <hip/hip_runtime.h>

typedef __attribute__((ext_vector_type(8))) short short8;
typedef __attribute__((ext_vector_type(4))) float float4v;

#define NLAGS 9
#define HID 256
#define GSAMP 16
#define MROWS 144          // 9 lag-tiles of 16 samples (LAG-MAJOR: row = lag*16 + samp)
#define NTHREADS 512
// 2 * 9 tiles * 4096 shorts (sL,sW) + 256 shorts (512B f32 scratch) = 147,968 B
#define SBUF_SHORTS (73728 + 256)

union S8 { short8 v; unsigned short u[8]; };

__device__ __forceinline__ unsigned short f2b(float f) {
  union { float f; unsigned int i; } c; c.f = f;
  return (unsigned short)((c.i + 0x7FFFu + ((c.i >> 16) & 1u)) >> 16);  // RNE
}
__device__ __forceinline__ float sane(float x) {
  return (__builtin_isfinite(x) && fabsf(x) < 1e30f) ? x : 0.0f;
}
// HW packed f32->bf16 (RNE), 1 VALU op for 2 conversions
__device__ __forceinline__ unsigned int pkbf16(float lo, float hi) {
  unsigned int r;
  asm("v_cvt_pk_bf16_f32 %0, %1, %2" : "=v"(r) : "v"(lo), "v"(hi));
  return r;
}
// unclamped tanh: exp->0 gives -1, exp->inf gives +1; finite-in => finite-out
// BLACKLIST (r8-r10 bisect): bias-init-in-MFMA-C and exp2f-tanh broke correctness.
__device__ __forceinline__ float ftanh(float x) {
  float t = __expf(2.0f * x);
  return 1.0f - 2.0f * __builtin_amdgcn_rcpf(t + 1.0f);
}
__device__ __forceinline__ float4v mfma16(short8 a, short8 b, float4v c) {
  return __builtin_amdgcn_mfma_f32_16x16x32_bf16(a, b, c, 0, 0, 0);
}

// ---- tile-major bf16 LDS layout: [tile m][kk-block of 32 cols][row 0..15][col&31]
__device__ __forceinline__ int tmC(int row, int c) {        // chunk c = col/8, 0..31
  return ((row >> 4) * 8 + (c >> 2)) * 512 + (row & 15) * 32 + (c & 3) * 8;
}
__device__ __forceinline__ int tmE(int row, int col) {      // single element
  return ((row >> 4) * 8 + (col >> 5)) * 512 + (row & 15) * 32 + (col & 31);
}

// ---- prep: f32 weights -> transposed bf16 copies in ws ----
// layout (bf16 elems): Wl2t[256][256] @0, Ww2t @65536, Ww1p[256][32] @131072
// (Wm1/Wm2 are NOT staged: merge1+merge2 both folded into T1/Tw/C0' below.)
__global__ void prep_kernel(const float* __restrict__ Wl2,
                            const float* __restrict__ Ww2,
                            const float* __restrict__ Ww1,
                            unsigned short* __restrict__ ws)
{
  int idx = blockIdx.x * 256 + threadIdx.x;   // 0..139263
  if (idx < 65536) {
    int n = idx >> 8, k = idx & 255;
    ws[idx] = f2b(sane(Wl2[k * 256 + n]));
  } else if (idx < 131072) {
    int j = idx - 65536; int n = j >> 8, k = j & 255;
    ws[idx] = f2b(sane(Ww2[k * 256 + n]));
  } else if (idx < 139264) {
    int j = idx - 131072; int n = j >> 5, k = j & 31;
    ws[idx] = (k < 8) ? f2b(sane(Ww1[k * 256 + n])) : (unsigned short)0;
  }
}

// ---- prep2a (verbatim r13/r14-verified algebra): V1, V2', C0 -> staging ----
// vtab staging (f32): V1 @5120 [9][256], V2' @7424 [9][256], C0 @9728
__global__ void prep2a_kernel(const float* __restrict__ Wm2,
                              const float* __restrict__ Wreg,
                              const float* __restrict__ bm2,
                              const float* __restrict__ breg,
                              float* __restrict__ vtab)
{
  const float A[9][9] = {
    {0,0,0,0,0,0,0,0,1},
    {1,0,0,0,0,0,0,0,0},
    {1.f/3,2.f/3,0,0,0,0,0,0,0},
    {0.2f,0.4f,0.4f,0,0,0,0,0,0},
    {0,0.2f,0.4f,0.4f,0,0,0,0,0},
    {0,0,0.2f,0.4f,0.4f,0,0,0,0},
    {0,0,0,0.2f,0.4f,0.4f,0,0,0},
    {0,0,0,0,0.25f,0.5f,0.25f,0,0},
    {0,0,0,0,0,1.f/3,1.f/3,1.f/3,0},
  };
  int idx = blockIdx.x * 256 + threadIdx.x;
  if (idx < 4608) {
    int mat = (idx >= 2304);              // 0: V1, 1: V2'
    int w = idx - mat * 2304;
    int d = w >> 8, k = w & 255;
    float coef[9];
    #pragma unroll
    for (int dp = 0; dp < 9; ++dp) {
      if (!mat) {
        coef[dp] = A[dp][d];              // (A^T)[d][dp]
      } else {
        float s = 0.f;                    // (A^2)[dp][d]
        #pragma unroll
        for (int e = 0; e < 9; ++e) s += A[dp][e] * A[e][d];
        coef[dp] = s;
      }
    }
    const float* wm2row = Wm2 + (size_t)(mat * 256 + k) * 256;
    float acc = 0.f;
    for (int h = 0; h < 256; ++h) {
      float wp = 0.f;
      #pragma unroll
      for (int dp = 0; dp < 9; ++dp) wp = fmaf(coef[dp], Wreg[dp * 256 + h], wp);
      acc = fmaf(wp, wm2row[h], acc);
    }
    vtab[5120 + idx] = acc;
  } else if (idx == 4608) {
    float c0 = breg[0];
    for (int d = 0; d < 9; ++d)
      for (int h = 0; h < 256; ++h) c0 = fmaf(bm2[h], Wreg[d * 256 + h], c0);
    vtab[9728] = c0;
  }
}

// ---- prep2b: fold merge1 too. U = A^T V1;
//   T1[s][k] = sum_h U[s][h] Wm1[k][h]            (k=0..255, l-part)
//   Tw[s][k] = sum_h U[s][h] Wm1[256+k][h] + V2'[s][k]
//   C0' = C0 + sum_{d,h} bm1[h] V1[d][h]
// final vtab: T1 @0 [9][256], Tw @2304 [9][256], C0' @4608
__global__ void prep2b_kernel(const float* __restrict__ Wm1,
                              const float* __restrict__ bm1,
                              float* __restrict__ vtab)
{
  const float A[9][9] = {
    {0,0,0,0,0,0,0,0,1},
    {1,0,0,0,0,0,0,0,0},
    {1.f/3,2.f/3,0,0,0,0,0,0,0},
    {0.2f,0.4f,0.4f,0,0,0,0,0,0},
    {0,0.2f,0.4f,0.4f,0,0,0,0,0},
    {0,0,0.2f,0.4f,0.4f,0,0,0,0},
    {0,0,0,0.2f,0.4f,0.4f,0,0,0},
    {0,0,0,0,0.25f,0.5f,0.25f,0,0},
    {0,0,0,0,0,1.f/3,1.f/3,1.f/3,0},
  };
  int idx = blockIdx.x * 256 + threadIdx.x;
  const float* V1s = vtab + 5120;
  const float* V2s = vtab + 7424;
  if (idx < 4608) {
    int mat = (idx >= 2304);              // 0: T1, 1: Tw
    int w = idx - mat * 2304;
    int s = w >> 8, k = w & 255;
    const float* wm1row = Wm1 + (size_t)(mat * 256 + k) * 256;
    float acc = 0.f;
    for (int h = 0; h < 256; ++h) {
      float u = 0.f;
      #pragma unroll
      for (int d = 0; d < 9; ++d) u = fmaf(A[d][s], V1s[d * 256 + h], u);
      acc = fmaf(u, wm1row[h], acc);
    }
    if (mat) acc += V2s[s * 256 + k];
    vtab[idx] = acc;
  } else if (idx == 4608) {
    float c = vtab[9728];
    for (int d = 0; d < 9; ++d)
      for (int h = 0; h < 256; ++h) c = fmaf(bm1[h], V1s[d * 256 + h], c);
    vtab[4608] = c;
  }
}

__global__ void __launch_bounds__(NTHREADS, 2)
fused_kernel(const float* __restrict__ lags,
             const float* __restrict__ weather,
             const float* __restrict__ Wl1,
             const float* __restrict__ bl1,
             const float* __restrict__ gbn,
             const float* __restrict__ bbn,
             const float* __restrict__ bl2,
             const float* __restrict__ bw1,
             const float* __restrict__ bw2,
             const unsigned short* __restrict__ ws,
             const float* __restrict__ vtab,
             float* __restrict__ out)
{
  __shared__ __align__(16) unsigned short sBuf[SBUF_SHORTS];  // 147,968 B
  unsigned short* sL = sBuf;
  unsigned short* sW = sBuf + 36864;      // 9 tiles * 4096 shorts
  float* scratch = (float*)(sBuf + 73728);

  const int tid = threadIdx.x;
  const int wave = tid >> 6;
  const int lane16 = tid & 15;
  const int g4 = (tid >> 4) & 3;
  const int s0 = blockIdx.x * GSAMP;

  const unsigned short* Wl2t = ws;
  const unsigned short* Ww2t = ws + 65536;
  const unsigned short* Ww1p = ws + 131072;

  const int c0 = wave * 32 + lane16;       // wave's two output columns
  const int c1 = wave * 32 + 16 + lane16;

  // ---- Phase A: l0 = BN(tanh(lag*Wl1+bl1)) -> sL, lag-major, tile-major ----
  {
    const float BNS = 0.99999500003750f;  // 1/sqrt(1+1e-5)
    const int samp = tid >> 5;            // 0..15
    const int chnk = tid & 31;            // fixed col chunk per thread
    const int h0 = chnk << 3;
    float4v w0 = *(const float4v*)(Wl1 + h0);
    float4v w1 = *(const float4v*)(Wl1 + h0 + 4);
    float4v a0 = *(const float4v*)(bl1 + h0);
    float4v a1 = *(const float4v*)(bl1 + h0 + 4);
    float4v g0 = *(const float4v*)(gbn + h0);
    float4v g1 = *(const float4v*)(gbn + h0 + 4);
    float4v q0 = *(const float4v*)(bbn + h0);
    float4v q1 = *(const float4v*)(bbn + h0 + 4);
    #pragma unroll
    for (int e = 0; e < 4; ++e) { g0[e] *= BNS; g1[e] *= BNS; }
    #pragma unroll
    for (int d = 0; d < 9; ++d) {         // d = lag
      int row = d * 16 + samp;
      float lag = lags[(s0 + samp) * NLAGS + d];
      float t[8];
      #pragma unroll
      for (int e = 0; e < 4; ++e) {
        float v = ftanh(fmaf(lag, w0[e], a0[e]));
        t[e] = fmaf(v, g0[e], q0[e]);
        float v2 = ftanh(fmaf(lag, w1[e], a1[e]));
        t[e + 4] = fmaf(v2, g1[e], q1[e]);
      }
      uint4 o;
      o.x = pkbf16(t[0], t[1]); o.y = pkbf16(t[2], t[3]);
      o.z = pkbf16(t[4], t[5]); o.w = pkbf16(t[6], t[7]);
      *(uint4*)(sL + tmC(row, chnk)) = o;
    }
  }

  // ---- Phase B: w0 = tanh(weather @ Ww1 + bw1) -> sW (K pad 8->32) ----
  {
    float4v acc0[9], acc1[9];
    short8 bf0 = *(const short8*)(Ww1p + c0 * 32 + g4 * 8);
    short8 bf1 = *(const short8*)(Ww1p + c1 * 32 + g4 * 8);
    #pragma unroll
    for (int m = 0; m < 9; ++m) {         // m = lag tile; row-in-tile = samp = lane16
      S8 a8;
      if (g4 == 0) {
        const float* wp = weather + (size_t)(s0 + lane16) * 72 + m * 8;
        float4v x0 = *(const float4v*)(wp);
        float4v x1 = *(const float4v*)(wp + 4);
        a8.v = (short8){0,0,0,0,0,0,0,0};
        unsigned int p0 = pkbf16(x0[0], x0[1]), p1 = pkbf16(x0[2], x0[3]);
        unsigned int p2 = pkbf16(x1[0], x1[1]), p3 = pkbf16(x1[2], x1[3]);
        a8.u[0] = (unsigned short)p0; a8.u[1] = (unsigned short)(p0 >> 16);
        a8.u[2] = (unsigned short)p1; a8.u[3] = (unsigned short)(p1 >> 16);
        a8.u[4] = (unsigned short)p2; a8.u[5] = (unsigned short)(p2 >> 16);
        a8.u[6] = (unsigned short)p3; a8.u[7] = (unsigned short)(p3 >> 16);
      } else {
        a8.v = (short8){0,0,0,0,0,0,0,0};
      }
      float4v zz = {0.f, 0.f, 0.f, 0.f};
      acc0[m] = mfma16(a8.v, bf0, zz);
      acc1[m] = mfma16(a8.v, bf1, zz);
    }
    float bia0 = bw1[c0], bia1 = bw1[c1];
    #pragma unroll
    for (int m = 0; m < 9; ++m) {
      #pragma unroll
      for (int i = 0; i < 4; ++i) {
        int row = m * 16 + g4 * 4 + i;    // C/D: col=lane&15, row=(lane>>4)*4+i
        unsigned int p = pkbf16(ftanh(acc0[m][i] + bia0), ftanh(acc1[m][i] + bia1));
        sW[tmE(row, c0)] = (unsigned short)p;
        sW[tmE(row, c1)] = (unsigned short)(p >> 16);
      }
    }
  }
  __syncthreads();   // B1: sL + sW published. NO further LDS writes until scratch.

  float P[4] = {0.f, 0.f, 0.f, 0.f};   // per-lane partial outputs, samples g4*4+i

  // ---- gemm-sL (K=256): l1 = tanh(l0@Wl2+bl2); epilogue: P += <l1, T1> ----
  {
    float4v acc0[9], acc1[9];
    #pragma unroll
    for (int m = 0; m < 9; ++m) {
      float4v z = {0.f,0.f,0.f,0.f};
      acc0[m] = z; acc1[m] = z;
    }
    #pragma unroll
    for (int kk = 0; kk < 8; ++kk) {
      short8 b0 = *(const short8*)(Wl2t + c0 * 256 + kk * 32 + g4 * 8);
      short8 b1 = *(const short8*)(Wl2t + c1 * 256 + kk * 32 + g4 * 8);
      #pragma unroll
      for (int m = 0; m < 9; ++m) {
        short8 a = *(const short8*)(sL + tmC(m * 16 + lane16, kk * 4 + g4));
        acc0[m] = mfma16(a, b0, acc0[m]);
        acc1[m] = mfma16(a, b1, acc1[m]);
      }
    }
    float t1c0[9], t1c1[9];
    #pragma unroll
    for (int m = 0; m < 9; ++m) {
      t1c0[m] = vtab[m * 256 + c0];     // T1[lag=m][col]
      t1c1[m] = vtab[m * 256 + c1];
    }
    float bia0 = bl2[c0], bia1 = bl2[c1];
    #pragma unroll
    for (int m = 0; m < 9; ++m) {
      #pragma unroll
      for (int i = 0; i < 4; ++i) {
        float t0 = ftanh(acc0[m][i] + bia0);   // l1, f32 (never quantized)
        float t1 = ftanh(acc1[m][i] + bia1);
        P[i] = fmaf(t0, t1c0[m], P[i]);
        P[i] = fmaf(t1, t1c1[m], P[i]);
      }
    }
  }

  // ---- gemm-sW (K=256): w1 = tanh(w0@Ww2+bw2); epilogue: P += <w1, Tw> ----
  {
    float4v acc0[9], acc1[9];
    #pragma unroll
    for (int m = 0; m < 9; ++m) {
      float4v z = {0.f,0.f,0.f,0.f};
      acc0[m] = z; acc1[m] = z;
    }
    #pragma unroll
    for (int kk = 0; kk < 8; ++kk) {
      short8 b0 = *(const short8*)(Ww2t + c0 * 256 + kk * 32 + g4 * 8);
      short8 b1 = *(const short8*)(Ww2t + c1 * 256 + kk * 32 + g4 * 8);
      #pragma unroll
      for (int m = 0; m < 9; ++m) {
        short8 a = *(const short8*)(sW + tmC(m * 16 + lane16, kk * 4 + g4));
        acc0[m] = mfma16(a, b0, acc0[m]);
        acc1[m] = mfma16(a, b1, acc1[m]);
      }
    }
    float twc0[9], twc1[9];
    #pragma unroll
    for (int m = 0; m < 9; ++m) {
      twc0[m] = vtab[2304 + m * 256 + c0];   // Tw[lag=m][col]
      twc1[m] = vtab[2304 + m * 256 + c1];
    }
    float bia0 = bw2[c0], bia1 = bw2[c1];
    #pragma unroll
    for (int m = 0; m < 9; ++m) {
      #pragma unroll
      for (int i = 0; i < 4; ++i) {
        float t0 = ftanh(acc0[m][i] + bia0);   // w1, f32
        float t1 = ftanh(acc1[m][i] + bia1);
        P[i] = fmaf(t0, twc0[m], P[i]);
        P[i] = fmaf(t1, twc1[m], P[i]);
      }
    }
  }

  // ---- reduce: cols (shfl within lane16 groups) then waves (scratch) ----
  #pragma unroll
  for (int off = 8; off >= 1; off >>= 1) {
    #pragma unroll
    for (int i = 0; i < 4; ++i) P[i] += __shfl_down(P[i], off, 16);
  }
  if (lane16 == 0) {
    #pragma unroll
    for (int i = 0; i < 4; ++i) scratch[wave * 16 + g4 * 4 + i] = P[i];
  }
  __syncthreads();   // B2: scratch published
  if (tid < GSAMP) {
    float sum = 0.f;
    #pragma unroll
    for (int w = 0; w < 8; ++w) sum += scratch[w * 16 + tid];
    out[s0 + tid] = sum + vtab[4608];     // + C0' (breg + bm2-fold + bm1-fold)
  }
}

extern "C" void kernel_launch(void* const* d_in, const int* in_sizes, int n_in,
                              void* d_out, int out_size, void* d_ws, size_t ws_size,
                              hipStream_t stream) {
  const float* lags    = (const float*)d_in[0];
  const float* weather = (const float*)d_in[1];
  const float* Wl1     = (const float*)d_in[2];
  const float* bl1     = (const float*)d_in[3];
  const float* gbn     = (const float*)d_in[4];
  const float* bbn     = (const float*)d_in[5];
  const float* Wl2     = (const float*)d_in[6];
  const float* bl2     = (const float*)d_in[7];
  const float* Ww1     = (const float*)d_in[8];
  const float* bw1     = (const float*)d_in[9];
  const float* Ww2     = (const float*)d_in[10];
  const float* bw2     = (const float*)d_in[11];
  const float* Wm1     = (const float*)d_in[12];
  const float* bm1     = (const float*)d_in[13];
  const float* Wm2     = (const float*)d_in[14];
  const float* bm2     = (const float*)d_in[15];
  const float* Wreg    = (const float*)d_in[16];
  const float* breg    = (const float*)d_in[17];
  unsigned short* ws = (unsigned short*)d_ws;
  float* vtab = (float*)(ws + 139264);    // byte offset 278,528 (16B-aligned)

  prep_kernel<<<544, 256, 0, stream>>>(Wl2, Ww2, Ww1, ws);
  prep2a_kernel<<<19, 256, 0, stream>>>(Wm2, Wreg, bm2, breg, vtab);
  prep2b_kernel<<<19, 256, 0, stream>>>(Wm1, bm1, vtab);

  const int nblocks = 32768 / GSAMP;  // 2048
  fused_kernel<<<nblocks, NTHREADS, 0, stream>>>(
      lags, weather, Wl1, bl1, gbn, bbn, bl2, bw1, bw2,
      ws, vtab, (float*)d_out);
}

// Round 16
// 251.454 us; speedup vs baseline: 1.6701x; 1.2758x over previous
//
#include <hip/hip_runtime.h>

typedef __attribute__((ext_vector_type(8))) short short8;
typedef __attribute__((ext_vector_type(4))) float float4v;

#define NLAGS 9
#define HID 256
#define GSAMP 16
#define MROWS 144          // 9 lag-tiles of 16 samples (LAG-MAJOR: row = lag*16 + samp)
#define NTHREADS 512
// 2 * 9 tiles * 4096 shorts (sL,sW) + 256 shorts (512B f32 scratch) = 147,968 B
#define SBUF_SHORTS (73728 + 256)

union S8 { short8 v; unsigned short u[8]; };

__device__ __forceinline__ unsigned short f2b(float f) {
  union { float f; unsigned int i; } c; c.f = f;
  return (unsigned short)((c.i + 0x7FFFu + ((c.i >> 16) & 1u)) >> 16);  // RNE
}
__device__ __forceinline__ float sane(float x) {
  return (__builtin_isfinite(x) && fabsf(x) < 1e30f) ? x : 0.0f;
}
// HW packed f32->bf16 (RNE), 1 VALU op for 2 conversions
__device__ __forceinline__ unsigned int pkbf16(float lo, float hi) {
  unsigned int r;
  asm("v_cvt_pk_bf16_f32 %0, %1, %2" : "=v"(r) : "v"(lo), "v"(hi));
  return r;
}
// unclamped tanh: exp->0 gives -1, exp->inf gives +1; finite-in => finite-out
// BLACKLIST (r8-r10 bisect): bias-init-in-MFMA-C and exp2f-tanh broke correctness.
__device__ __forceinline__ float ftanh(float x) {
  float t = __expf(2.0f * x);
  return 1.0f - 2.0f * __builtin_amdgcn_rcpf(t + 1.0f);
}
__device__ __forceinline__ float4v mfma16(short8 a, short8 b, float4v c) {
  return __builtin_amdgcn_mfma_f32_16x16x32_bf16(a, b, c, 0, 0, 0);
}

// ---- tile-major bf16 LDS layout: [tile m][kk-block of 32 cols][row 0..15][col&31]
__device__ __forceinline__ int tmC(int row, int c) {        // chunk c = col/8, 0..31
  return ((row >> 4) * 8 + (c >> 2)) * 512 + (row & 15) * 32 + (c & 3) * 8;
}
__device__ __forceinline__ int tmE(int row, int col) {      // single element
  return ((row >> 4) * 8 + (col >> 5)) * 512 + (row & 15) * 32 + (col & 31);
}

#define A_TABLE { \
    {0,0,0,0,0,0,0,0,1}, \
    {1,0,0,0,0,0,0,0,0}, \
    {1.f/3,2.f/3,0,0,0,0,0,0,0}, \
    {0.2f,0.4f,0.4f,0,0,0,0,0,0}, \
    {0,0.2f,0.4f,0.4f,0,0,0,0,0}, \
    {0,0,0.2f,0.4f,0.4f,0,0,0,0}, \
    {0,0,0,0.2f,0.4f,0.4f,0,0,0}, \
    {0,0,0,0,0.25f,0.5f,0.25f,0,0}, \
    {0,0,0,0,0,1.f/3,1.f/3,1.f/3,0}, \
  }

// ---- prep_all: (blocks 0..271) f32 weights -> transposed bf16 ws tables;
//      (blocks 272..848) prep2a wave-per-output: V1/V2'/C0 -> vtab staging.
// ws (bf16): Wl2t[256][256] @0, Ww2t @65536, Ww1p[256][32] @131072 (K pad 8->32)
// vtab staging (f32): V1 @5120 [9][256], V2' @7424 [9][256], C0 @9728
//   V1  = (A^T Wreg) @ Wm2top^T ; V2' = (A^T A^T Wreg) @ Wm2bot^T
//   C0  = breg + sum_h bm2[h] * (sum_d Wreg[d*256+h])
__global__ void prep_all(const float* __restrict__ Wl2,
                         const float* __restrict__ Ww2,
                         const float* __restrict__ Ww1,
                         const float* __restrict__ Wm2,
                         const float* __restrict__ Wreg,
                         const float* __restrict__ bm2,
                         const float* __restrict__ breg,
                         unsigned short* __restrict__ ws,
                         float* __restrict__ vtab)
{
  const int b = blockIdx.x;
  if (b < 272) {
    int idx = b * 512 + threadIdx.x;   // 0..139263
    if (idx < 65536) {
      int n = idx >> 8, k = idx & 255;
      ws[idx] = f2b(sane(Wl2[k * 256 + n]));
    } else if (idx < 131072) {
      int j = idx - 65536; int n = j >> 8, k = j & 255;
      ws[idx] = f2b(sane(Ww2[k * 256 + n]));
    } else if (idx < 139264) {
      int j = idx - 131072; int n = j >> 5, k = j & 31;
      ws[idx] = (k < 8) ? f2b(sane(Ww1[k * 256 + n])) : (unsigned short)0;
    }
    return;
  }
  // ---- prep2a: one wave per output element (identical algebra to r14/r15) ----
  const float A[9][9] = A_TABLE;
  const int lane = threadIdx.x & 63;
  const int g = (b - 272) * 8 + (threadIdx.x >> 6);
  if (g < 4608) {
    int mat = (g >= 2304);              // 0: V1, 1: V2'
    int w = g - mat * 2304;
    int d = w >> 8, k = w & 255;
    float coef[9];
    #pragma unroll
    for (int dp = 0; dp < 9; ++dp) {
      if (!mat) {
        coef[dp] = A[dp][d];            // (A^T)[d][dp]
      } else {
        float s = 0.f;                  // (A^2)[dp][d]
        #pragma unroll
        for (int e = 0; e < 9; ++e) s += A[dp][e] * A[e][d];
        coef[dp] = s;
      }
    }
    const float* wm2row = Wm2 + (size_t)(mat * 256 + k) * 256;
    float acc = 0.f;
    #pragma unroll
    for (int it = 0; it < 4; ++it) {
      int h = lane + it * 64;           // coalesced across the wave
      float wp = 0.f;
      #pragma unroll
      for (int dp = 0; dp < 9; ++dp) wp = fmaf(coef[dp], Wreg[dp * 256 + h], wp);
      acc = fmaf(wp, wm2row[h], acc);
    }
    #pragma unroll
    for (int off = 32; off >= 1; off >>= 1) acc += __shfl_down(acc, off);
    if (lane == 0) vtab[5120 + g] = acc;
  } else if (g == 4608) {
    float c0 = 0.f;
    #pragma unroll
    for (int it = 0; it < 4; ++it) {
      int h = lane + it * 64;
      float cs = 0.f;
      #pragma unroll
      for (int d = 0; d < 9; ++d) cs += Wreg[d * 256 + h];
      c0 = fmaf(bm2[h], cs, c0);
    }
    #pragma unroll
    for (int off = 32; off >= 1; off >>= 1) c0 += __shfl_down(c0, off);
    if (lane == 0) vtab[9728] = c0 + breg[0];
  }
}

// ---- prep2b: wave-per-output.  U = A^T V1;
//   T1[s][k] = sum_h U[s][h] Wm1[k][h]
//   Tw[s][k] = sum_h U[s][h] Wm1[256+k][h] + V2'[s][k]
//   C0' = C0 + sum_h bm1[h] * (sum_d V1[d*256+h])
// final vtab: T1 @0 [9][256], Tw @2304 [9][256], C0' @4608
__global__ void prep2b_kernel(const float* __restrict__ Wm1,
                              const float* __restrict__ bm1,
                              float* __restrict__ vtab)
{
  const float A[9][9] = A_TABLE;
  const float* V1s = vtab + 5120;
  const float* V2s = vtab + 7424;
  const int lane = threadIdx.x & 63;
  const int g = blockIdx.x * 8 + (threadIdx.x >> 6);
  if (g < 4608) {
    int mat = (g >= 2304);              // 0: T1, 1: Tw
    int w = g - mat * 2304;
    int s = w >> 8, k = w & 255;
    const float* wm1row = Wm1 + (size_t)(mat * 256 + k) * 256;
    float acc = 0.f;
    #pragma unroll
    for (int it = 0; it < 4; ++it) {
      int h = lane + it * 64;
      float u = 0.f;
      #pragma unroll
      for (int d = 0; d < 9; ++d) u = fmaf(A[d][s], V1s[d * 256 + h], u);
      acc = fmaf(u, wm1row[h], acc);
    }
    #pragma unroll
    for (int off = 32; off >= 1; off >>= 1) acc += __shfl_down(acc, off);
    if (lane == 0) vtab[g] = acc + (mat ? V2s[s * 256 + k] : 0.f);
  } else if (g == 4608) {
    float c = 0.f;
    #pragma unroll
    for (int it = 0; it < 4; ++it) {
      int h = lane + it * 64;
      float vs = 0.f;
      #pragma unroll
      for (int d = 0; d < 9; ++d) vs += V1s[d * 256 + h];
      c = fmaf(bm1[h], vs, c);
    }
    #pragma unroll
    for (int off = 32; off >= 1; off >>= 1) c += __shfl_down(c, off);
    if (lane == 0) vtab[4608] = c + vtab[9728];
  }
}

__global__ void __launch_bounds__(NTHREADS, 2)
fused_kernel(const float* __restrict__ lags,
             const float* __restrict__ weather,
             const float* __restrict__ Wl1,
             const float* __restrict__ bl1,
             const float* __restrict__ gbn,
             const float* __restrict__ bbn,
             const float* __restrict__ bl2,
             const float* __restrict__ bw1,
             const float* __restrict__ bw2,
             const unsigned short* __restrict__ ws,
             const float* __restrict__ vtab,
             float* __restrict__ out)
{
  __shared__ __align__(16) unsigned short sBuf[SBUF_SHORTS];  // 147,968 B
  unsigned short* sL = sBuf;
  unsigned short* sW = sBuf + 36864;      // 9 tiles * 4096 shorts
  float* scratch = (float*)(sBuf + 73728);

  const int tid = threadIdx.x;
  const int wave = tid >> 6;
  const int lane16 = tid & 15;
  const int g4 = (tid >> 4) & 3;
  const int s0 = blockIdx.x * GSAMP;

  const unsigned short* Wl2t = ws;
  const unsigned short* Ww2t = ws + 65536;
  const unsigned short* Ww1p = ws + 131072;

  const int c0 = wave * 32 + lane16;       // wave's two output columns
  const int c1 = wave * 32 + 16 + lane16;

  // ---- Phase A: l0 = BN(tanh(lag*Wl1+bl1)) -> sL, lag-major, tile-major ----
  {
    const float BNS = 0.99999500003750f;  // 1/sqrt(1+1e-5)
    const int samp = tid >> 5;            // 0..15
    const int chnk = tid & 31;            // fixed col chunk per thread
    const int h0 = chnk << 3;
    float4v w0 = *(const float4v*)(Wl1 + h0);
    float4v w1 = *(const float4v*)(Wl1 + h0 + 4);
    float4v a0 = *(const float4v*)(bl1 + h0);
    float4v a1 = *(const float4v*)(bl1 + h0 + 4);
    float4v g0 = *(const float4v*)(gbn + h0);
    float4v g1 = *(const float4v*)(gbn + h0 + 4);
    float4v q0 = *(const float4v*)(bbn + h0);
    float4v q1 = *(const float4v*)(bbn + h0 + 4);
    #pragma unroll
    for (int e = 0; e < 4; ++e) { g0[e] *= BNS; g1[e] *= BNS; }
    #pragma unroll
    for (int d = 0; d < 9; ++d) {         // d = lag
      int row = d * 16 + samp;
      float lag = lags[(s0 + samp) * NLAGS + d];
      float t[8];
      #pragma unroll
      for (int e = 0; e < 4; ++e) {
        float v = ftanh(fmaf(lag, w0[e], a0[e]));
        t[e] = fmaf(v, g0[e], q0[e]);
        float v2 = ftanh(fmaf(lag, w1[e], a1[e]));
        t[e + 4] = fmaf(v2, g1[e], q1[e]);
      }
      uint4 o;
      o.x = pkbf16(t[0], t[1]); o.y = pkbf16(t[2], t[3]);
      o.z = pkbf16(t[4], t[5]); o.w = pkbf16(t[6], t[7]);
      *(uint4*)(sL + tmC(row, chnk)) = o;
    }
  }

  // ---- Phase B: w0 = tanh(weather @ Ww1 + bw1) -> sW (K pad 8->32) ----
  {
    float4v acc0[9], acc1[9];
    short8 bf0 = *(const short8*)(Ww1p + c0 * 32 + g4 * 8);
    short8 bf1 = *(const short8*)(Ww1p + c1 * 32 + g4 * 8);
    #pragma unroll
    for (int m = 0; m < 9; ++m) {         // m = lag tile; row-in-tile = samp = lane16
      S8 a8;
      if (g4 == 0) {
        const float* wp = weather + (size_t)(s0 + lane16) * 72 + m * 8;
        float4v x0 = *(const float4v*)(wp);
        float4v x1 = *(const float4v*)(wp + 4);
        a8.v = (short8){0,0,0,0,0,0,0,0};
        unsigned int p0 = pkbf16(x0[0], x0[1]), p1 = pkbf16(x0[2], x0[3]);
        unsigned int p2 = pkbf16(x1[0], x1[1]), p3 = pkbf16(x1[2], x1[3]);
        a8.u[0] = (unsigned short)p0; a8.u[1] = (unsigned short)(p0 >> 16);
        a8.u[2] = (unsigned short)p1; a8.u[3] = (unsigned short)(p1 >> 16);
        a8.u[4] = (unsigned short)p2; a8.u[5] = (unsigned short)(p2 >> 16);
        a8.u[6] = (unsigned short)p3; a8.u[7] = (unsigned short)(p3 >> 16);
      } else {
        a8.v = (short8){0,0,0,0,0,0,0,0};
      }
      float4v zz = {0.f, 0.f, 0.f, 0.f};
      acc0[m] = mfma16(a8.v, bf0, zz);
      acc1[m] = mfma16(a8.v, bf1, zz);
    }
    float bia0 = bw1[c0], bia1 = bw1[c1];
    #pragma unroll
    for (int m = 0; m < 9; ++m) {
      #pragma unroll
      for (int i = 0; i < 4; ++i) {
        int row = m * 16 + g4 * 4 + i;    // C/D: col=lane&15, row=(lane>>4)*4+i
        unsigned int p = pkbf16(ftanh(acc0[m][i] + bia0), ftanh(acc1[m][i] + bia1));
        sW[tmE(row, c0)] = (unsigned short)p;
        sW[tmE(row, c1)] = (unsigned short)(p >> 16);
      }
    }
  }
  __syncthreads();   // B1: sL + sW published. NO further LDS writes until scratch.

  float P[4] = {0.f, 0.f, 0.f, 0.f};   // per-lane partial outputs, samples g4*4+i

  // ---- gemm-sL (K=256): l1 = tanh(l0@Wl2+bl2); epilogue: P += <l1, T1> ----
  {
    float4v acc0[9], acc1[9];
    #pragma unroll
    for (int m = 0; m < 9; ++m) {
      float4v z = {0.f,0.f,0.f,0.f};
      acc0[m] = z; acc1[m] = z;
    }
    #pragma unroll
    for (int kk = 0; kk < 8; ++kk) {
      short8 b0 = *(const short8*)(Wl2t + c0 * 256 + kk * 32 + g4 * 8);
      short8 b1 = *(const short8*)(Wl2t + c1 * 256 + kk * 32 + g4 * 8);
      #pragma unroll
      for (int m = 0; m < 9; ++m) {
        short8 a = *(const short8*)(sL + tmC(m * 16 + lane16, kk * 4 + g4));
        acc0[m] = mfma16(a, b0, acc0[m]);
        acc1[m] = mfma16(a, b1, acc1[m]);
      }
    }
    float t1c0[9], t1c1[9];
    #pragma unroll
    for (int m = 0; m < 9; ++m) {
      t1c0[m] = vtab[m * 256 + c0];     // T1[lag=m][col]
      t1c1[m] = vtab[m * 256 + c1];
    }
    float bia0 = bl2[c0], bia1 = bl2[c1];
    #pragma unroll
    for (int m = 0; m < 9; ++m) {
      #pragma unroll
      for (int i = 0; i < 4; ++i) {
        float t0 = ftanh(acc0[m][i] + bia0);   // l1, f32 (never quantized)
        float t1 = ftanh(acc1[m][i] + bia1);
        P[i] = fmaf(t0, t1c0[m], P[i]);
        P[i] = fmaf(t1, t1c1[m], P[i]);
      }
    }
  }

  // ---- gemm-sW (K=256): w1 = tanh(w0@Ww2+bw2); epilogue: P += <w1, Tw> ----
  {
    float4v acc0[9], acc1[9];
    #pragma unroll
    for (int m = 0; m < 9; ++m) {
      float4v z = {0.f,0.f,0.f,0.f};
      acc0[m] = z; acc1[m] = z;
    }
    #pragma unroll
    for (int kk = 0; kk < 8; ++kk) {
      short8 b0 = *(const short8*)(Ww2t + c0 * 256 + kk * 32 + g4 * 8);
      short8 b1 = *(const short8*)(Ww2t + c1 * 256 + kk * 32 + g4 * 8);
      #pragma unroll
      for (int m = 0; m < 9; ++m) {
        short8 a = *(const short8*)(sW + tmC(m * 16 + lane16, kk * 4 + g4));
        acc0[m] = mfma16(a, b0, acc0[m]);
        acc1[m] = mfma16(a, b1, acc1[m]);
      }
    }
    float twc0[9], twc1[9];
    #pragma unroll
    for (int m = 0; m < 9; ++m) {
      twc0[m] = vtab[2304 + m * 256 + c0];   // Tw[lag=m][col]
      twc1[m] = vtab[2304 + m * 256 + c1];
    }
    float bia0 = bw2[c0], bia1 = bw2[c1];
    #pragma unroll
    for (int m = 0; m < 9; ++m) {
      #pragma unroll
      for (int i = 0; i < 4; ++i) {
        float t0 = ftanh(acc0[m][i] + bia0);   // w1, f32
        float t1 = ftanh(acc1[m][i] + bia1);
        P[i] = fmaf(t0, twc0[m], P[i]);
        P[i] = fmaf(t1, twc1[m], P[i]);
      }
    }
  }

  // ---- reduce: cols (shfl within lane16 groups) then waves (scratch) ----
  #pragma unroll
  for (int off = 8; off >= 1; off >>= 1) {
    #pragma unroll
    for (int i = 0; i < 4; ++i) P[i] += __shfl_down(P[i], off, 16);
  }
  if (lane16 == 0) {
    #pragma unroll
    for (int i = 0; i < 4; ++i) scratch[wave * 16 + g4 * 4 + i] = P[i];
  }
  __syncthreads();   // B2: scratch published
  if (tid < GSAMP) {
    float sum = 0.f;
    #pragma unroll
    for (int w = 0; w < 8; ++w) sum += scratch[w * 16 + tid];
    out[s0 + tid] = sum + vtab[4608];     // + C0' (breg + bm2-fold + bm1-fold)
  }
}

extern "C" void kernel_launch(void* const* d_in, const int* in_sizes, int n_in,
                              void* d_out, int out_size, void* d_ws, size_t ws_size,
                              hipStream_t stream) {
  const float* lags    = (const float*)d_in[0];
  const float* weather = (const float*)d_in[1];
  const float* Wl1     = (const float*)d_in[2];
  const float* bl1     = (const float*)d_in[3];
  const float* gbn     = (const float*)d_in[4];
  const float* bbn     = (const float*)d_in[5];
  const float* Wl2     = (const float*)d_in[6];
  const float* bl2     = (const float*)d_in[7];
  const float* Ww1     = (const float*)d_in[8];
  const float* bw1     = (const float*)d_in[9];
  const float* Ww2     = (const float*)d_in[10];
  const float* bw2     = (const float*)d_in[11];
  const float* Wm1     = (const float*)d_in[12];
  const float* bm1     = (const float*)d_in[13];
  const float* Wm2     = (const float*)d_in[14];
  const float* bm2     = (const float*)d_in[15];
  const float* Wreg    = (const float*)d_in[16];
  const float* breg    = (const float*)d_in[17];
  unsigned short* ws = (unsigned short*)d_ws;
  float* vtab = (float*)(ws + 139264);    // byte offset 278,528 (16B-aligned)

  // prep_all: 272 staging blocks + 577 prep2a wave-blocks = 849
  prep_all<<<849, 512, 0, stream>>>(Wl2, Ww2, Ww1, Wm2, Wreg, bm2, breg, ws, vtab);
  prep2b_kernel<<<577, 512, 0, stream>>>(Wm1, bm1, vtab);

  const int nblocks = 32768 / GSAMP;  // 2048
  fused_kernel<<<nblocks, NTHREADS, 0, stream>>>(
      lags, weather, Wl1, bl1, gbn, bbn, bl2, bw1, bw2,
      ws, vtab, (float*)d_out);
}